// Round 3
// baseline (1669.685 us; speedup 1.0000x reference)
//
#include <hip/hip_runtime.h>
#include <math.h>
#include <stdint.h>

#define NND 20000
#define DIMK 512
#define NE  320000
#define GRID 1024

typedef __attribute__((ext_vector_type(8))) short short8;
typedef __attribute__((ext_vector_type(4))) float floatx4;

__device__ inline float bf2f(unsigned short h) {
    unsigned int u = ((unsigned int)h) << 16;
    return __uint_as_float(u);
}
__device__ inline unsigned short f2bf(float f) {
    unsigned int u = __float_as_uint(f);
    unsigned int r = (u + 0x7fffu + ((u >> 16) & 1u)) >> 16;
    return (unsigned short)r;
}

__device__ __forceinline__ void gld_lds16(const unsigned short* g, unsigned short* l) {
    __builtin_amdgcn_global_load_lds(
        (const __attribute__((address_space(1))) void*)g,
        (__attribute__((address_space(3))) void*)l,
        16, 0, 0);
}

// Grid barrier: single monotonic counter, zeroed by host memset each replay.
// All GRID blocks are resident by construction (launch_bounds(256,4) -> 4
// blocks/CU x 256 CU = 1024). Agent-scope fences per Guideline 16.
__device__ __forceinline__ void gbar(int* cnt) {
    __syncthreads();
    if (threadIdx.x == 0) {
        __threadfence();
        int v = __hip_atomic_fetch_add(cnt, 1, __ATOMIC_ACQ_REL, __HIP_MEMORY_SCOPE_AGENT);
        int target = (v / GRID + 1) * GRID;
        while (__hip_atomic_load(cnt, __ATOMIC_ACQUIRE, __HIP_MEMORY_SCOPE_AGENT) < target) {
            __builtin_amdgcn_s_sleep(2);
        }
        __threadfence();
    }
    __syncthreads();
}

// 128x128x512 bf16 GEMM tile (double-buffered, XOR-swizzled LDS), vb = tile id.
__device__ __forceinline__ void gemm_tile(int vb,
                                          const unsigned short* __restrict__ A,
                                          const unsigned short* __restrict__ B,
                                          const float* __restrict__ biasf,
                                          unsigned short* __restrict__ out_q,
                                          float* __restrict__ out_f,
                                          int M, int MT, int NT, int Ncols,
                                          unsigned short* smem) {
    int xcd = vb & 7, i = vb >> 3;
    int nt = i % NT, mt = (i / NT) * 8 + xcd;
    if (mt >= MT) return;
    int m0 = mt * 128, n0 = nt * 128;
    int tid = threadIdx.x, wv = tid >> 6, ln = tid & 63;
    int lr = ln & 15, qd = ln >> 4;
    int mh = wv >> 1, nh = wv & 1;

    floatx4 acc[4][4] = {};
    int srow = wv * 16 + (ln >> 2);
    int scol = (((ln & 3) ^ (ln >> 4)) & 3) * 8;
    int fsw = (qd ^ (lr >> 2)) & 3;

    {
        unsigned short* Ab = smem;
        unsigned short* Bb = smem + 8192;
#pragma unroll
        for (int p = 0; p < 2; p++) {
            int tr = p * 64 + srow;
            int ar = m0 + tr; if (ar > M - 1) ar = M - 1;
            gld_lds16(A + (size_t)ar * DIMK + scol, Ab + (p * 64 + wv * 16) * 32);
            gld_lds16(B + (size_t)(n0 + tr) * DIMK + scol, Bb + (p * 64 + wv * 16) * 32);
        }
    }

    for (int it = 0; it < 16; it++) {
        int cur = it & 1, nxt = cur ^ 1;
        __syncthreads();
        if (it + 1 < 16) {
            int kb = (it + 1) * 32;
            unsigned short* Ab = smem + nxt * 4096;
            unsigned short* Bb = smem + 8192 + nxt * 4096;
#pragma unroll
            for (int p = 0; p < 2; p++) {
                int tr = p * 64 + srow;
                int ar = m0 + tr; if (ar > M - 1) ar = M - 1;
                gld_lds16(A + (size_t)ar * DIMK + kb + scol, Ab + (p * 64 + wv * 16) * 32);
                gld_lds16(B + (size_t)(n0 + tr) * DIMK + kb + scol, Bb + (p * 64 + wv * 16) * 32);
            }
        }
        const unsigned short* Ac = smem + cur * 4096;
        const unsigned short* Bc = smem + 8192 + cur * 4096;
        short8 af[4], bfr[4];
#pragma unroll
        for (int mi = 0; mi < 4; mi++)
            af[mi] = *(const short8*)(Ac + (mh * 64 + mi * 16 + lr) * 32 + fsw * 8);
#pragma unroll
        for (int ni = 0; ni < 4; ni++)
            bfr[ni] = *(const short8*)(Bc + (nh * 64 + ni * 16 + lr) * 32 + fsw * 8);
#pragma unroll
        for (int mi = 0; mi < 4; mi++)
#pragma unroll
            for (int ni = 0; ni < 4; ni++)
                acc[mi][ni] = __builtin_amdgcn_mfma_f32_16x16x32_bf16(af[mi], bfr[ni], acc[mi][ni], 0, 0, 0);
    }

    float bb[4];
#pragma unroll
    for (int ni = 0; ni < 4; ni++) bb[ni] = biasf[n0 + nh * 64 + ni * 16 + lr];

    if (!out_f) {
        int col0 = nt * 128;
        unsigned short* cs = smem;
#pragma unroll
        for (int g = 0; g < 4; g++) {
            __syncthreads();
            if (mh == (g >> 1)) {
                int miB = (g & 1) * 2;
#pragma unroll
                for (int m2 = 0; m2 < 2; m2++) {
                    int mi = miB + m2;
                    int lrow = mi * 16 + qd * 4 - (g & 1) * 32;
#pragma unroll
                    for (int ni = 0; ni < 4; ni++) {
                        int col = nh * 64 + ni * 16 + lr;
#pragma unroll
                        for (int r = 0; r < 4; r++)
                            cs[(lrow + r) * 128 + col] = f2bf(acc[mi][ni][r] + bb[ni]);
                    }
                }
            }
            __syncthreads();
#pragma unroll
            for (int itr = 0; itr < 2; itr++) {
                int slot = itr * 256 + tid;
                int row = slot >> 4, cg = slot & 15;
                int gm = m0 + g * 32 + row;
                if (gm < M) {
                    short8 vv = *(const short8*)(cs + row * 128 + cg * 8);
                    *(short8*)(out_q + (size_t)gm * 512 + col0 + cg * 8) = vv;
                }
            }
        }
    } else {
#pragma unroll
        for (int ni = 0; ni < 4; ni++) {
            int gn = n0 + nh * 64 + ni * 16 + lr;
#pragma unroll
            for (int mi = 0; mi < 4; mi++) {
                int gm0 = m0 + mh * 64 + mi * 16 + qd * 4;
#pragma unroll
                for (int r = 0; r < 4; r++) {
                    int gm = gm0 + r;
                    if (gm < M) out_f[(size_t)gm * Ncols + gn] = acc[mi][ni][r] + bb[ni];
                }
            }
        }
    }
}

// ---------------- single persistent kernel: all phases ------------------------
__global__ __launch_bounds__(256, 4) void k_all(const float* __restrict__ x,
                                                const int* __restrict__ src,
                                                const int* __restrict__ dst,
                                                const float* __restrict__ Wq,
                                                const float* __restrict__ bq,
                                                const float* __restrict__ Wk,
                                                const float* __restrict__ Wv,
                                                const float* __restrict__ bv,
                                                const float* __restrict__ Wo,
                                                const float* __restrict__ bo,
                                                float* __restrict__ out,
                                                unsigned short* __restrict__ t,
                                                unsigned short* __restrict__ qh,
                                                unsigned short* __restrict__ WqTs,
                                                unsigned short* __restrict__ WkT,
                                                unsigned short* __restrict__ WvT,
                                                unsigned short* __restrict__ WoB,
                                                unsigned short* __restrict__ Amat,
                                                unsigned short* __restrict__ Wovb,
                                                float* __restrict__ bh,
                                                float* __restrict__ bpr,
                                                int* __restrict__ ssrc,
                                                int* __restrict__ offsets,
                                                int* __restrict__ pos,
                                                int* __restrict__ counts,
                                                int* __restrict__ bars,
                                                float scf) {
    __shared__ __align__(16) char smraw[32768];
    unsigned short* smem = (unsigned short*)smraw;
    int tid = threadIdx.x;
    int* bar_cnt = bars;       // zeroed by host memset each replay
    int* gtotal  = bars + 1;   // zeroed by host memset each replay

    // ---- P0: logmap, weight cvt/transposes, bias folds, dst histogram ----
    for (int vb = blockIdx.x; vb < 6954; vb += GRID) {
        if (vb < 5000) {
            int row = vb * 4 + (tid >> 6);
            int lane = tid & 63;
            const floatx4* xp = (const floatx4*)(x + (size_t)row * DIMK + lane * 8);
            floatx4 x0 = xp[0], x1 = xp[1];
            float ss = 0.f;
#pragma unroll
            for (int i = 0; i < 4; i++) { ss += x0[i] * x0[i]; ss += x1[i] * x1[i]; }
#pragma unroll
            for (int off = 32; off >= 1; off >>= 1) ss += __shfl_xor(ss, off, 64);
            float n  = sqrtf(ss);
            float nc = fminf(fmaxf(n, 1e-7f), 1.0f - 1e-6f);
            float fac = atanhf(nc) / nc;
            union { short8 v; unsigned short u[8]; } o;
#pragma unroll
            for (int i = 0; i < 4; i++) { o.u[i] = f2bf(fac * x0[i]); o.u[4 + i] = f2bf(fac * x1[i]); }
            *(short8*)(t + (size_t)row * DIMK + lane * 8) = o.v;
        } else if (vb < 5256) {
            int i = (vb - 5000) * 256 + tid;
            floatx4 f = *(const floatx4*)(Wo + (size_t)i * 4);
            union { unsigned long long d; unsigned short u[4]; } o;
#pragma unroll
            for (int q = 0; q < 4; q++) o.u[q] = f2bf(f[q]);
            *(unsigned long long*)(WoB + (size_t)i * 4) = o.d;
        } else if (vb < 5448) {
            int g = vb - 5256;
            int m = g >> 6, tile = g & 63;
            int tr = tile >> 3, tc = tile & 7;
            const float* srcm = (m == 0) ? Wq : (m == 1) ? Wk : Wv;
            unsigned short* dstp = (m == 0) ? WqTs : (m == 1) ? WkT : WvT;
            float sc = (m == 0) ? scf : 1.0f;
            float (*tl)[65] = (float (*)[65])smraw;
#pragma unroll
            for (int i = 0; i < 16; i++) {
                int idx = i * 256 + tid; int r = idx >> 6, c = idx & 63;
                tl[c][r] = srcm[(size_t)(tr * 64 + r) * 512 + tc * 64 + c];
            }
            __syncthreads();
#pragma unroll
            for (int i = 0; i < 16; i++) {
                int idx = i * 256 + tid; int r = idx >> 6, c = idx & 63;
                dstp[(size_t)(tc * 64 + r) * 512 + tr * 64 + c] = f2bf(tl[r][c] * sc);
            }
            __syncthreads();
        } else if (vb < 5576) {
            // bh[col] = scf * sum_m bq[m]*Wk[m][col]; 4 cols per vblock
            int col = (vb - 5448) * 4 + (tid >> 6);
            int lane = tid & 63;
            int m0 = lane * 8;
            float s = 0.f;
#pragma unroll
            for (int j = 0; j < 8; j++) s += bq[m0 + j] * Wk[(size_t)(m0 + j) * 512 + col];
#pragma unroll
            for (int off = 32; off >= 1; off >>= 1) s += __shfl_xor(s, off, 64);
            if (lane == 0) bh[col] = s * scf;
        } else if (vb < 5704) {
            int row = (vb - 5576) * 4 + (tid >> 6);
            int lane = tid & 63;
            const floatx4* wp = (const floatx4*)(Wo + (size_t)row * 512 + lane * 8);
            const floatx4* bp = (const floatx4*)(bv + lane * 8);
            floatx4 a0 = wp[0], a1 = wp[1], c0 = bp[0], c1 = bp[1];
            float s = 0.f;
#pragma unroll
            for (int i = 0; i < 4; i++) { s += a0[i] * c0[i]; s += a1[i] * c1[i]; }
#pragma unroll
            for (int off = 32; off >= 1; off >>= 1) s += __shfl_xor(s, off, 64);
            if (lane == 0) bpr[row] = s + bo[row];
        } else {
            int e = (vb - 5704) * 256 + tid;
            if (e < NE) atomicAdd(&counts[dst[e]], 1);
        }
    }
    gbar(bar_cnt);

    // ---- P1: scan-free segment allocation (order-independent CSR) ----
    if (blockIdx.x < 1000 && tid < 64) {
        int b = blockIdx.x;
        int lane = tid;
        int c = (lane < 20) ? counts[b * 20 + lane] : 0;
        int p = c;
#pragma unroll
        for (int off = 1; off < 32; off <<= 1) {
            int u = __shfl_up(p, off, 64);
            if (lane >= off) p += u;
        }
        int excl = p - c;
        int btot = __shfl(p, 19, 64);
        int base;
        if (lane == 0) base = atomicAdd(gtotal, btot);
        base = __shfl(base, 0, 64);
        if (lane < 20) {
            int o = base + excl;
            offsets[b * 20 + lane] = o;
            pos[b * 20 + lane] = o;
        }
    }
    gbar(bar_cnt);

    // ---- P2: edge scatter + the two 512^3 weight products ----
    for (int vb = blockIdx.x; vb < 1282; vb += GRID) {
        if (vb < 1250) {
            int e = vb * 256 + tid;
            if (e < NE) { int p = atomicAdd(&pos[dst[e]], 1); ssrc[p] = src[e]; }
        } else {
            int g = vb - 1250;                   // 0..31
            int prod = g >> 4;
            int mt = (g >> 2) & 3, nt = g & 3;
            const unsigned short* A = prod ? WoB : WkT;
            const unsigned short* B = prod ? WvT : WqTs;
            unsigned short* outp = prod ? Wovb : Amat;
            int m0 = mt * 128, n0 = nt * 128;
            int wv = tid >> 6, ln = tid & 63;
            int lr = ln & 15, qd = ln >> 4;
            int mh = wv >> 1, nh = wv & 1;
            floatx4 acc[4][4] = {};
            int srow = wv * 16 + (ln >> 2);
            int scol = (((ln & 3) ^ (ln >> 4)) & 3) * 8;
            int fsw = (qd ^ (lr >> 2)) & 3;
            {
                unsigned short* Ab = smem;
                unsigned short* Bb = smem + 8192;
#pragma unroll
                for (int p = 0; p < 2; p++) {
                    int tr = p * 64 + srow;
                    gld_lds16(A + (size_t)(m0 + tr) * DIMK + scol, Ab + (p * 64 + wv * 16) * 32);
                    gld_lds16(B + (size_t)(n0 + tr) * DIMK + scol, Bb + (p * 64 + wv * 16) * 32);
                }
            }
            for (int it = 0; it < 16; it++) {
                int cur = it & 1, nxt = cur ^ 1;
                __syncthreads();
                if (it + 1 < 16) {
                    int kb = (it + 1) * 32;
                    unsigned short* Ab = smem + nxt * 4096;
                    unsigned short* Bb = smem + 8192 + nxt * 4096;
#pragma unroll
                    for (int p = 0; p < 2; p++) {
                        int tr = p * 64 + srow;
                        gld_lds16(A + (size_t)(m0 + tr) * DIMK + kb + scol, Ab + (p * 64 + wv * 16) * 32);
                        gld_lds16(B + (size_t)(n0 + tr) * DIMK + kb + scol, Bb + (p * 64 + wv * 16) * 32);
                    }
                }
                const unsigned short* Ac = smem + cur * 4096;
                const unsigned short* Bc = smem + 8192 + cur * 4096;
                short8 af[4], bfr[4];
#pragma unroll
                for (int mi = 0; mi < 4; mi++)
                    af[mi] = *(const short8*)(Ac + (mh * 64 + mi * 16 + lr) * 32 + fsw * 8);
#pragma unroll
                for (int ni = 0; ni < 4; ni++)
                    bfr[ni] = *(const short8*)(Bc + (nh * 64 + ni * 16 + lr) * 32 + fsw * 8);
#pragma unroll
                for (int mi = 0; mi < 4; mi++)
#pragma unroll
                    for (int ni = 0; ni < 4; ni++)
                        acc[mi][ni] = __builtin_amdgcn_mfma_f32_16x16x32_bf16(af[mi], bfr[ni], acc[mi][ni], 0, 0, 0);
            }
#pragma unroll
            for (int ni = 0; ni < 4; ni++) {
                int gn = n0 + nh * 64 + ni * 16 + lr;
#pragma unroll
                for (int mi = 0; mi < 4; mi++) {
                    int gm0 = m0 + mh * 64 + mi * 16 + qd * 4;
#pragma unroll
                    for (int r = 0; r < 4; r++)
                        outp[(size_t)(gm0 + r) * 512 + gn] = f2bf(acc[mi][ni][r]);
                }
            }
        }
    }
    gbar(bar_cnt);

    // ---- P3: qh = t @ Amat^T + bh (bf16) ----
    for (int vb = blockIdx.x; vb < 640; vb += GRID)
        gemm_tile(vb, t, Amat, bh, qh, nullptr, NND, 157, 4, 512, smem);
    gbar(bar_cnt);

    // ---- P4: fused score+softmax+aggregate ----
    {
        float (*sacc)[512] = (float (*)[512])smraw;
        float* sden = (float*)(smraw + 4 * 512 * 4);
        int wv = tid >> 6, ln = tid & 63;
        for (int n = blockIdx.x; n < NND; n += GRID) {
            int beg = offsets[n], end = beg + counts[n];
            union { short8 v; unsigned short u[8]; } qu;
            qu.v = *(const short8*)(qh + (size_t)n * 512 + ln * 8);
            float qf[8];
#pragma unroll
            for (int j = 0; j < 8; j++) qf[j] = bf2f(qu.u[j]);
            float av[8] = {0, 0, 0, 0, 0, 0, 0, 0};
            float den = 0.f;
            int i = beg + wv * 2;
            for (; i + 1 < end; i += 8) {
                const unsigned short* p0 = t + (size_t)ssrc[i] * 512 + ln * 8;
                const unsigned short* p1 = t + (size_t)ssrc[i + 1] * 512 + ln * 8;
                union { short8 v; unsigned short u[8]; } r0, r1;
                r0.v = *(const short8*)p0;
                r1.v = *(const short8*)p1;
                float t0[8], t1[8];
                float d0 = 0.f, d1 = 0.f;
#pragma unroll
                for (int j = 0; j < 8; j++) {
                    t0[j] = bf2f(r0.u[j]); d0 += qf[j] * t0[j];
                    t1[j] = bf2f(r1.u[j]); d1 += qf[j] * t1[j];
                }
#pragma unroll
                for (int off = 32; off >= 1; off >>= 1) {
                    d0 += __shfl_xor(d0, off, 64);
                    d1 += __shfl_xor(d1, off, 64);
                }
                float w0 = __expf(d0), w1 = __expf(d1);
                den += w0 + w1;
#pragma unroll
                for (int j = 0; j < 8; j++) av[j] += w0 * t0[j] + w1 * t1[j];
            }
            if (i < end) {
                const unsigned short* p0 = t + (size_t)ssrc[i] * 512 + ln * 8;
                union { short8 v; unsigned short u[8]; } r0;
                r0.v = *(const short8*)p0;
                float t0[8];
                float d0 = 0.f;
#pragma unroll
                for (int j = 0; j < 8; j++) { t0[j] = bf2f(r0.u[j]); d0 += qf[j] * t0[j]; }
#pragma unroll
                for (int off = 32; off >= 1; off >>= 1) d0 += __shfl_xor(d0, off, 64);
                float w0 = __expf(d0);
                den += w0;
#pragma unroll
                for (int j = 0; j < 8; j++) av[j] += w0 * t0[j];
            }
            floatx4 s0v = {av[0], av[1], av[2], av[3]};
            floatx4 s1v = {av[4], av[5], av[6], av[7]};
            *(floatx4*)&sacc[wv][ln * 8]     = s0v;
            *(floatx4*)&sacc[wv][ln * 8 + 4] = s1v;
            if (ln == 0) sden[wv] = den;
            __syncthreads();
            float inv = 1.0f / (sden[0] + sden[1] + sden[2] + sden[3]);
            int c = tid * 2;
            float t0 = sacc[0][c] + sacc[1][c] + sacc[2][c] + sacc[3][c];
            float t1 = sacc[0][c + 1] + sacc[1][c + 1] + sacc[2][c + 1] + sacc[3][c + 1];
            qh[(size_t)n * 512 + c]     = f2bf(t0 * inv);   // attn aliases qh
            qh[(size_t)n * 512 + c + 1] = f2bf(t1 * inv);
            __syncthreads();
        }
    }
    gbar(bar_cnt);

    // ---- P5: out = attn @ Wovb^T + bpr (fp32) ----
    for (int vb = blockIdx.x; vb < 640; vb += GRID)
        gemm_tile(vb, qh, Wovb, bpr, nullptr, out, NND, 157, 4, 512, smem);
    gbar(bar_cnt);

    // ---- P6: expmap0 in place ----
    for (int vb = blockIdx.x; vb < 5000; vb += GRID) {
        int row = vb * 4 + (tid >> 6);
        int lane = tid & 63;
        floatx4* hp = (floatx4*)(out + (size_t)row * DIMK + lane * 8);
        floatx4 h0 = hp[0], h1 = hp[1];
        float ss = 0.f;
#pragma unroll
        for (int i = 0; i < 4; i++) { ss += h0[i] * h0[i]; ss += h1[i] * h1[i]; }
#pragma unroll
        for (int off = 32; off >= 1; off >>= 1) ss += __shfl_xor(ss, off, 64);
        float n  = sqrtf(ss);
        float nc = fmaxf(n, 1e-7f);
        float fac = tanhf(nc) / nc;
#pragma unroll
        for (int i = 0; i < 4; i++) { h0[i] *= fac; h1[i] *= fac; }
        hp[0] = h0; hp[1] = h1;
    }
}

extern "C" void kernel_launch(void* const* d_in, const int* in_sizes, int n_in,
                              void* d_out, int out_size, void* d_ws, size_t ws_size,
                              hipStream_t stream) {
    const float* x  = (const float*)d_in[0];
    const int* src  = (const int*)d_in[1];
    const int* dst  = (const int*)d_in[2];
    const float* Wq = (const float*)d_in[3];
    const float* bq = (const float*)d_in[4];
    const float* Wk = (const float*)d_in[5];
    const float* Wv = (const float*)d_in[7];
    const float* bv = (const float*)d_in[8];
    const float* Wo = (const float*)d_in[9];
    const float* bo = (const float*)d_in[10];
    float* out = (float*)d_out;

    char* ws = (char*)d_ws;
    const size_t RB  = (size_t)NND * DIMK * 2;     // 20.48 MB bf16 [N,512]
    const size_t WB  = (size_t)DIMK * DIMK * 2;    // 512 KB bf16 [512,512]
    unsigned short* t    = (unsigned short*)(ws);
    unsigned short* qh   = (unsigned short*)(ws + RB);      // attn aliases qh
    unsigned short* WqTs = (unsigned short*)(ws + 2 * RB);
    unsigned short* WkT  = (unsigned short*)(ws + 2 * RB + WB);
    unsigned short* WvT  = (unsigned short*)(ws + 2 * RB + 2 * WB);
    unsigned short* WoB  = (unsigned short*)(ws + 2 * RB + 3 * WB);
    unsigned short* Amat = (unsigned short*)(ws + 2 * RB + 4 * WB);
    unsigned short* Wovb = (unsigned short*)(ws + 2 * RB + 5 * WB);
    float* bh            = (float*)(ws + 2 * RB + 6 * WB);
    float* bpr           = (float*)(ws + 2 * RB + 6 * WB + 2048);
    char* p = ws + 2 * RB + 6 * WB + 4096;
    int* ssrc    = (int*)p;
    int* offsets = ssrc + NE;
    int* pos     = offsets + NND + 2;
    int* bars    = pos + NND + 2;       // [0]=bar_cnt [1]=gtotal [2..7] pad
    int* counts  = bars + 8;            // contiguous with bars for one memset

    // zero barrier counter + segment cursor + histogram in ONE memset node
    hipMemsetAsync(bars, 0, (size_t)(8 + NND) * 4, stream);

    const float scf = 0.04419417382415922f;        // 1/sqrt(512)
    k_all<<<GRID, 256, 0, stream>>>(x, src, dst, Wq, bq, Wk, Wv, bv, Wo, bo, out,
                                    t, qh, WqTs, WkT, WvT, WoB, Amat, Wovb,
                                    bh, bpr, ssrc, offsets, pos, counts, bars, scf);
}

// Round 4
// 801.623 us; speedup vs baseline: 2.0829x; 2.0829x over previous
//
#include <hip/hip_runtime.h>
#include <math.h>
#include <stdint.h>

#define NND 20000
#define DIMK 512
#define NE  320000
#define GRID 1024

typedef __attribute__((ext_vector_type(8))) short short8;
typedef __attribute__((ext_vector_type(4))) float floatx4;

__device__ inline float bf2f(unsigned short h) {
    unsigned int u = ((unsigned int)h) << 16;
    return __uint_as_float(u);
}
__device__ inline unsigned short f2bf(float f) {
    unsigned int u = __float_as_uint(f);
    unsigned int r = (u + 0x7fffu + ((u >> 16) & 1u)) >> 16;
    return (unsigned short)r;
}

__device__ __forceinline__ void gld_lds16(const unsigned short* g, unsigned short* l) {
    __builtin_amdgcn_global_load_lds(
        (const __attribute__((address_space(1))) void*)g,
        (__attribute__((address_space(3))) void*)l,
        16, 0, 0);
}

// Grid barrier with RELAXED polling. The R3 version polled with ACQUIRE
// agent-scope loads -> buffer_inv per poll -> every spinning wave wiped its
// XCD's L2 every ~128cy (death spiral, 5.9x regression). Now: one RELEASE
// fence (L2 wb) before arrival, relaxed add, relaxed polls with s_sleep
// backoff, one ACQUIRE fence (L2 inv) after release. Counter zeroed by host
// memset each replay; all GRID blocks resident (launch_bounds(256,4)).
__device__ __forceinline__ void gbar(int* cnt) {
    __syncthreads();
    if (threadIdx.x == 0) {
        __builtin_amdgcn_fence(__ATOMIC_RELEASE, "agent");
        int v = __hip_atomic_fetch_add(cnt, 1, __ATOMIC_RELAXED, __HIP_MEMORY_SCOPE_AGENT);
        int target = (v / GRID + 1) * GRID;
        while (__hip_atomic_load(cnt, __ATOMIC_RELAXED, __HIP_MEMORY_SCOPE_AGENT) < target)
            __builtin_amdgcn_s_sleep(16);
        __builtin_amdgcn_fence(__ATOMIC_ACQUIRE, "agent");
    }
    __syncthreads();
}

// 128x128x512 bf16 GEMM tile (double-buffered, XOR-swizzled LDS), vb = tile id.
__device__ __forceinline__ void gemm_tile(int vb,
                                          const unsigned short* __restrict__ A,
                                          const unsigned short* __restrict__ B,
                                          const float* __restrict__ biasf,
                                          unsigned short* __restrict__ out_q,
                                          float* __restrict__ out_f,
                                          int M, int MT, int NT, int Ncols,
                                          unsigned short* smem) {
    int xcd = vb & 7, i = vb >> 3;
    int nt = i % NT, mt = (i / NT) * 8 + xcd;
    if (mt >= MT) return;
    int m0 = mt * 128, n0 = nt * 128;
    int tid = threadIdx.x, wv = tid >> 6, ln = tid & 63;
    int lr = ln & 15, qd = ln >> 4;
    int mh = wv >> 1, nh = wv & 1;

    floatx4 acc[4][4] = {};
    int srow = wv * 16 + (ln >> 2);
    int scol = (((ln & 3) ^ (ln >> 4)) & 3) * 8;
    int fsw = (qd ^ (lr >> 2)) & 3;

    {
        unsigned short* Ab = smem;
        unsigned short* Bb = smem + 8192;
#pragma unroll
        for (int p = 0; p < 2; p++) {
            int tr = p * 64 + srow;
            int ar = m0 + tr; if (ar > M - 1) ar = M - 1;
            gld_lds16(A + (size_t)ar * DIMK + scol, Ab + (p * 64 + wv * 16) * 32);
            gld_lds16(B + (size_t)(n0 + tr) * DIMK + scol, Bb + (p * 64 + wv * 16) * 32);
        }
    }

    for (int it = 0; it < 16; it++) {
        int cur = it & 1, nxt = cur ^ 1;
        __syncthreads();
        if (it + 1 < 16) {
            int kb = (it + 1) * 32;
            unsigned short* Ab = smem + nxt * 4096;
            unsigned short* Bb = smem + 8192 + nxt * 4096;
#pragma unroll
            for (int p = 0; p < 2; p++) {
                int tr = p * 64 + srow;
                int ar = m0 + tr; if (ar > M - 1) ar = M - 1;
                gld_lds16(A + (size_t)ar * DIMK + kb + scol, Ab + (p * 64 + wv * 16) * 32);
                gld_lds16(B + (size_t)(n0 + tr) * DIMK + kb + scol, Bb + (p * 64 + wv * 16) * 32);
            }
        }
        const unsigned short* Ac = smem + cur * 4096;
        const unsigned short* Bc = smem + 8192 + cur * 4096;
        short8 af[4], bfr[4];
#pragma unroll
        for (int mi = 0; mi < 4; mi++)
            af[mi] = *(const short8*)(Ac + (mh * 64 + mi * 16 + lr) * 32 + fsw * 8);
#pragma unroll
        for (int ni = 0; ni < 4; ni++)
            bfr[ni] = *(const short8*)(Bc + (nh * 64 + ni * 16 + lr) * 32 + fsw * 8);
#pragma unroll
        for (int mi = 0; mi < 4; mi++)
#pragma unroll
            for (int ni = 0; ni < 4; ni++)
                acc[mi][ni] = __builtin_amdgcn_mfma_f32_16x16x32_bf16(af[mi], bfr[ni], acc[mi][ni], 0, 0, 0);
    }

    float bb[4];
#pragma unroll
    for (int ni = 0; ni < 4; ni++) bb[ni] = biasf[n0 + nh * 64 + ni * 16 + lr];

    if (!out_f) {
        int col0 = nt * 128;
        unsigned short* cs = smem;
#pragma unroll
        for (int g = 0; g < 4; g++) {
            __syncthreads();
            if (mh == (g >> 1)) {
                int miB = (g & 1) * 2;
#pragma unroll
                for (int m2 = 0; m2 < 2; m2++) {
                    int mi = miB + m2;
                    int lrow = mi * 16 + qd * 4 - (g & 1) * 32;
#pragma unroll
                    for (int ni = 0; ni < 4; ni++) {
                        int col = nh * 64 + ni * 16 + lr;
#pragma unroll
                        for (int r = 0; r < 4; r++)
                            cs[(lrow + r) * 128 + col] = f2bf(acc[mi][ni][r] + bb[ni]);
                    }
                }
            }
            __syncthreads();
#pragma unroll
            for (int itr = 0; itr < 2; itr++) {
                int slot = itr * 256 + tid;
                int row = slot >> 4, cg = slot & 15;
                int gm = m0 + g * 32 + row;
                if (gm < M) {
                    short8 vv = *(const short8*)(cs + row * 128 + cg * 8);
                    *(short8*)(out_q + (size_t)gm * 512 + col0 + cg * 8) = vv;
                }
            }
        }
    } else {
#pragma unroll
        for (int ni = 0; ni < 4; ni++) {
            int gn = n0 + nh * 64 + ni * 16 + lr;
#pragma unroll
            for (int mi = 0; mi < 4; mi++) {
                int gm0 = m0 + mh * 64 + mi * 16 + qd * 4;
#pragma unroll
                for (int r = 0; r < 4; r++) {
                    int gm = gm0 + r;
                    if (gm < M) out_f[(size_t)gm * Ncols + gn] = acc[mi][ni][r] + bb[ni];
                }
            }
        }
    }
}

// ---------------- single persistent kernel: all phases ------------------------
__global__ __launch_bounds__(256, 4) void k_all(const float* __restrict__ x,
                                                const int* __restrict__ src,
                                                const int* __restrict__ dst,
                                                const float* __restrict__ Wq,
                                                const float* __restrict__ bq,
                                                const float* __restrict__ Wk,
                                                const float* __restrict__ Wv,
                                                const float* __restrict__ bv,
                                                const float* __restrict__ Wo,
                                                const float* __restrict__ bo,
                                                float* __restrict__ out,
                                                unsigned short* __restrict__ t,
                                                unsigned short* __restrict__ qh,
                                                unsigned short* __restrict__ WqTs,
                                                unsigned short* __restrict__ WkT,
                                                unsigned short* __restrict__ WvT,
                                                unsigned short* __restrict__ WoB,
                                                unsigned short* __restrict__ Amat,
                                                unsigned short* __restrict__ Wovb,
                                                float* __restrict__ bh,
                                                float* __restrict__ bpr,
                                                int* __restrict__ ssrc,
                                                int* __restrict__ offsets,
                                                int* __restrict__ pos,
                                                int* __restrict__ counts,
                                                int* __restrict__ bars,
                                                float scf) {
    __shared__ __align__(16) char smraw[32768];
    unsigned short* smem = (unsigned short*)smraw;
    int tid = threadIdx.x;
    int* bar_cnt = bars;       // zeroed by host memset each replay
    int* gtotal  = bars + 1;   // zeroed by host memset each replay

    // ---- P0: logmap, weight cvt/transposes, bias folds, dst histogram ----
    for (int vb = blockIdx.x; vb < 6954; vb += GRID) {
        if (vb < 5000) {
            int row = vb * 4 + (tid >> 6);
            int lane = tid & 63;
            const floatx4* xp = (const floatx4*)(x + (size_t)row * DIMK + lane * 8);
            floatx4 x0 = xp[0], x1 = xp[1];
            float ss = 0.f;
#pragma unroll
            for (int i = 0; i < 4; i++) { ss += x0[i] * x0[i]; ss += x1[i] * x1[i]; }
#pragma unroll
            for (int off = 32; off >= 1; off >>= 1) ss += __shfl_xor(ss, off, 64);
            float n  = sqrtf(ss);
            float nc = fminf(fmaxf(n, 1e-7f), 1.0f - 1e-6f);
            float fac = atanhf(nc) / nc;
            union { short8 v; unsigned short u[8]; } o;
#pragma unroll
            for (int i = 0; i < 4; i++) { o.u[i] = f2bf(fac * x0[i]); o.u[4 + i] = f2bf(fac * x1[i]); }
            *(short8*)(t + (size_t)row * DIMK + lane * 8) = o.v;
        } else if (vb < 5256) {
            int i = (vb - 5000) * 256 + tid;
            floatx4 f = *(const floatx4*)(Wo + (size_t)i * 4);
            union { unsigned long long d; unsigned short u[4]; } o;
#pragma unroll
            for (int q = 0; q < 4; q++) o.u[q] = f2bf(f[q]);
            *(unsigned long long*)(WoB + (size_t)i * 4) = o.d;
        } else if (vb < 5448) {
            int g = vb - 5256;
            int m = g >> 6, tile = g & 63;
            int tr = tile >> 3, tc = tile & 7;
            const float* srcm = (m == 0) ? Wq : (m == 1) ? Wk : Wv;
            unsigned short* dstp = (m == 0) ? WqTs : (m == 1) ? WkT : WvT;
            float sc = (m == 0) ? scf : 1.0f;
            float (*tl)[65] = (float (*)[65])smraw;
            __syncthreads();
#pragma unroll
            for (int i = 0; i < 16; i++) {
                int idx = i * 256 + tid; int r = idx >> 6, c = idx & 63;
                tl[c][r] = srcm[(size_t)(tr * 64 + r) * 512 + tc * 64 + c];
            }
            __syncthreads();
#pragma unroll
            for (int i = 0; i < 16; i++) {
                int idx = i * 256 + tid; int r = idx >> 6, c = idx & 63;
                dstp[(size_t)(tc * 64 + r) * 512 + tr * 64 + c] = f2bf(tl[r][c] * sc);
            }
        } else if (vb < 5576) {
            // bh[col] = scf * sum_m bq[m]*Wk[m][col]; 4 cols per vblock
            int col = (vb - 5448) * 4 + (tid >> 6);
            int lane = tid & 63;
            int m0 = lane * 8;
            float s = 0.f;
#pragma unroll
            for (int j = 0; j < 8; j++) s += bq[m0 + j] * Wk[(size_t)(m0 + j) * 512 + col];
#pragma unroll
            for (int off = 32; off >= 1; off >>= 1) s += __shfl_xor(s, off, 64);
            if (lane == 0) bh[col] = s * scf;
        } else if (vb < 5704) {
            int row = (vb - 5576) * 4 + (tid >> 6);
            int lane = tid & 63;
            const floatx4* wp = (const floatx4*)(Wo + (size_t)row * 512 + lane * 8);
            const floatx4* bp = (const floatx4*)(bv + lane * 8);
            floatx4 a0 = wp[0], a1 = wp[1], c0 = bp[0], c1 = bp[1];
            float s = 0.f;
#pragma unroll
            for (int i = 0; i < 4; i++) { s += a0[i] * c0[i]; s += a1[i] * c1[i]; }
#pragma unroll
            for (int off = 32; off >= 1; off >>= 1) s += __shfl_xor(s, off, 64);
            if (lane == 0) bpr[row] = s + bo[row];
        } else {
            int e = (vb - 5704) * 256 + tid;
            if (e < NE) atomicAdd(&counts[dst[e]], 1);
        }
    }
    gbar(bar_cnt);

    // ---- P1: seg-alloc scan (vb<1000) + the two 512^3 weight products ----
    for (int vb = blockIdx.x; vb < 1032; vb += GRID) {
        if (vb < 1000) {
            if (tid < 64) {
                int lane = tid;
                int c = (lane < 20) ? counts[vb * 20 + lane] : 0;
                int p = c;
#pragma unroll
                for (int off = 1; off < 32; off <<= 1) {
                    int u = __shfl_up(p, off, 64);
                    if (lane >= off) p += u;
                }
                int excl = p - c;
                int btot = __shfl(p, 19, 64);
                int base;
                if (lane == 0) base = atomicAdd(gtotal, btot);
                base = __shfl(base, 0, 64);
                if (lane < 20) {
                    int o = base + excl;
                    offsets[vb * 20 + lane] = o;
                    pos[vb * 20 + lane] = o;
                }
            }
        } else {
            int g = vb - 1000;                   // 0..31
            int prod = g >> 4;
            int mt = (g >> 2) & 3, nt = g & 3;
            const unsigned short* A = prod ? WoB : WkT;
            const unsigned short* B = prod ? WvT : WqTs;
            unsigned short* outp = prod ? Wovb : Amat;
            int m0 = mt * 128, n0 = nt * 128;
            int wv = tid >> 6, ln = tid & 63;
            int lr = ln & 15, qd = ln >> 4;
            int mh = wv >> 1, nh = wv & 1;
            floatx4 acc[4][4] = {};
            int srow = wv * 16 + (ln >> 2);
            int scol = (((ln & 3) ^ (ln >> 4)) & 3) * 8;
            int fsw = (qd ^ (lr >> 2)) & 3;
            {
                unsigned short* Ab = smem;
                unsigned short* Bb = smem + 8192;
#pragma unroll
                for (int p = 0; p < 2; p++) {
                    int tr = p * 64 + srow;
                    gld_lds16(A + (size_t)(m0 + tr) * DIMK + scol, Ab + (p * 64 + wv * 16) * 32);
                    gld_lds16(B + (size_t)(n0 + tr) * DIMK + scol, Bb + (p * 64 + wv * 16) * 32);
                }
            }
            for (int it = 0; it < 16; it++) {
                int cur = it & 1, nxt = cur ^ 1;
                __syncthreads();
                if (it + 1 < 16) {
                    int kb = (it + 1) * 32;
                    unsigned short* Ab = smem + nxt * 4096;
                    unsigned short* Bb = smem + 8192 + nxt * 4096;
#pragma unroll
                    for (int p = 0; p < 2; p++) {
                        int tr = p * 64 + srow;
                        gld_lds16(A + (size_t)(m0 + tr) * DIMK + kb + scol, Ab + (p * 64 + wv * 16) * 32);
                        gld_lds16(B + (size_t)(n0 + tr) * DIMK + kb + scol, Bb + (p * 64 + wv * 16) * 32);
                    }
                }
                const unsigned short* Ac = smem + cur * 4096;
                const unsigned short* Bc = smem + 8192 + cur * 4096;
                short8 af[4], bfr[4];
#pragma unroll
                for (int mi = 0; mi < 4; mi++)
                    af[mi] = *(const short8*)(Ac + (mh * 64 + mi * 16 + lr) * 32 + fsw * 8);
#pragma unroll
                for (int ni = 0; ni < 4; ni++)
                    bfr[ni] = *(const short8*)(Bc + (nh * 64 + ni * 16 + lr) * 32 + fsw * 8);
#pragma unroll
                for (int mi = 0; mi < 4; mi++)
#pragma unroll
                    for (int ni = 0; ni < 4; ni++)
                        acc[mi][ni] = __builtin_amdgcn_mfma_f32_16x16x32_bf16(af[mi], bfr[ni], acc[mi][ni], 0, 0, 0);
            }
#pragma unroll
            for (int ni = 0; ni < 4; ni++) {
                int gn = n0 + nh * 64 + ni * 16 + lr;
#pragma unroll
                for (int mi = 0; mi < 4; mi++) {
                    int gm0 = m0 + mh * 64 + mi * 16 + qd * 4;
#pragma unroll
                    for (int r = 0; r < 4; r++)
                        outp[(size_t)(gm0 + r) * 512 + gn] = f2bf(acc[mi][ni][r]);
                }
            }
        }
    }
    gbar(bar_cnt);

    // ---- P2: qh GEMM (vb<640, needs Amat) + edge scatter (needs offsets) ----
    for (int vb = blockIdx.x; vb < 1890; vb += GRID) {
        if (vb < 640) {
            gemm_tile(vb, t, Amat, bh, qh, nullptr, NND, 157, 4, 512, smem);
        } else {
            int e = (vb - 640) * 256 + tid;
            if (e < NE) { int p = atomicAdd(&pos[dst[e]], 1); ssrc[p] = src[e]; }
        }
    }
    gbar(bar_cnt);

    // ---- P3: fused score+softmax+aggregate ----
    {
        float (*sacc)[512] = (float (*)[512])smraw;
        float* sden = (float*)(smraw + 4 * 512 * 4);
        int wv = tid >> 6, ln = tid & 63;
        for (int n = blockIdx.x; n < NND; n += GRID) {
            int beg = offsets[n], end = beg + counts[n];
            union { short8 v; unsigned short u[8]; } qu;
            qu.v = *(const short8*)(qh + (size_t)n * 512 + ln * 8);
            float qf[8];
#pragma unroll
            for (int j = 0; j < 8; j++) qf[j] = bf2f(qu.u[j]);
            float av[8] = {0, 0, 0, 0, 0, 0, 0, 0};
            float den = 0.f;
            int i = beg + wv * 2;
            for (; i + 1 < end; i += 8) {
                const unsigned short* p0 = t + (size_t)ssrc[i] * 512 + ln * 8;
                const unsigned short* p1 = t + (size_t)ssrc[i + 1] * 512 + ln * 8;
                union { short8 v; unsigned short u[8]; } r0, r1;
                r0.v = *(const short8*)p0;
                r1.v = *(const short8*)p1;
                float t0[8], t1[8];
                float d0 = 0.f, d1 = 0.f;
#pragma unroll
                for (int j = 0; j < 8; j++) {
                    t0[j] = bf2f(r0.u[j]); d0 += qf[j] * t0[j];
                    t1[j] = bf2f(r1.u[j]); d1 += qf[j] * t1[j];
                }
#pragma unroll
                for (int off = 32; off >= 1; off >>= 1) {
                    d0 += __shfl_xor(d0, off, 64);
                    d1 += __shfl_xor(d1, off, 64);
                }
                float w0 = __expf(d0), w1 = __expf(d1);
                den += w0 + w1;
#pragma unroll
                for (int j = 0; j < 8; j++) av[j] += w0 * t0[j] + w1 * t1[j];
            }
            if (i < end) {
                const unsigned short* p0 = t + (size_t)ssrc[i] * 512 + ln * 8;
                union { short8 v; unsigned short u[8]; } r0;
                r0.v = *(const short8*)p0;
                float t0[8];
                float d0 = 0.f;
#pragma unroll
                for (int j = 0; j < 8; j++) { t0[j] = bf2f(r0.u[j]); d0 += qf[j] * t0[j]; }
#pragma unroll
                for (int off = 32; off >= 1; off >>= 1) d0 += __shfl_xor(d0, off, 64);
                float w0 = __expf(d0);
                den += w0;
#pragma unroll
                for (int j = 0; j < 8; j++) av[j] += w0 * t0[j];
            }
            floatx4 s0v = {av[0], av[1], av[2], av[3]};
            floatx4 s1v = {av[4], av[5], av[6], av[7]};
            *(floatx4*)&sacc[wv][ln * 8]     = s0v;
            *(floatx4*)&sacc[wv][ln * 8 + 4] = s1v;
            if (ln == 0) sden[wv] = den;
            __syncthreads();
            float inv = 1.0f / (sden[0] + sden[1] + sden[2] + sden[3]);
            int c = tid * 2;
            float t0 = sacc[0][c] + sacc[1][c] + sacc[2][c] + sacc[3][c];
            float t1 = sacc[0][c + 1] + sacc[1][c + 1] + sacc[2][c + 1] + sacc[3][c + 1];
            qh[(size_t)n * 512 + c]     = f2bf(t0 * inv);   // attn aliases qh
            qh[(size_t)n * 512 + c + 1] = f2bf(t1 * inv);
            __syncthreads();
        }
    }
    gbar(bar_cnt);

    // ---- P4: out = attn @ Wovb^T + bpr (fp32) ----
    for (int vb = blockIdx.x; vb < 640; vb += GRID)
        gemm_tile(vb, qh, Wovb, bpr, nullptr, out, NND, 157, 4, 512, smem);
    gbar(bar_cnt);

    // ---- P5: expmap0 in place ----
    for (int vb = blockIdx.x; vb < 5000; vb += GRID) {
        int row = vb * 4 + (tid >> 6);
        int lane = tid & 63;
        floatx4* hp = (floatx4*)(out + (size_t)row * DIMK + lane * 8);
        floatx4 h0 = hp[0], h1 = hp[1];
        float ss = 0.f;
#pragma unroll
        for (int i = 0; i < 4; i++) { ss += h0[i] * h0[i]; ss += h1[i] * h1[i]; }
#pragma unroll
        for (int off = 32; off >= 1; off >>= 1) ss += __shfl_xor(ss, off, 64);
        float n  = sqrtf(ss);
        float nc = fmaxf(n, 1e-7f);
        float fac = tanhf(nc) / nc;
#pragma unroll
        for (int i = 0; i < 4; i++) { h0[i] *= fac; h1[i] *= fac; }
        hp[0] = h0; hp[1] = h1;
    }
}

extern "C" void kernel_launch(void* const* d_in, const int* in_sizes, int n_in,
                              void* d_out, int out_size, void* d_ws, size_t ws_size,
                              hipStream_t stream) {
    const float* x  = (const float*)d_in[0];
    const int* src  = (const int*)d_in[1];
    const int* dst  = (const int*)d_in[2];
    const float* Wq = (const float*)d_in[3];
    const float* bq = (const float*)d_in[4];
    const float* Wk = (const float*)d_in[5];
    const float* Wv = (const float*)d_in[7];
    const float* bv = (const float*)d_in[8];
    const float* Wo = (const float*)d_in[9];
    const float* bo = (const float*)d_in[10];
    float* out = (float*)d_out;

    char* ws = (char*)d_ws;
    const size_t RB  = (size_t)NND * DIMK * 2;     // 20.48 MB bf16 [N,512]
    const size_t WB  = (size_t)DIMK * DIMK * 2;    // 512 KB bf16 [512,512]
    unsigned short* t    = (unsigned short*)(ws);
    unsigned short* qh   = (unsigned short*)(ws + RB);      // attn aliases qh
    unsigned short* WqTs = (unsigned short*)(ws + 2 * RB);
    unsigned short* WkT  = (unsigned short*)(ws + 2 * RB + WB);
    unsigned short* WvT  = (unsigned short*)(ws + 2 * RB + 2 * WB);
    unsigned short* WoB  = (unsigned short*)(ws + 2 * RB + 3 * WB);
    unsigned short* Amat = (unsigned short*)(ws + 2 * RB + 4 * WB);
    unsigned short* Wovb = (unsigned short*)(ws + 2 * RB + 5 * WB);
    float* bh            = (float*)(ws + 2 * RB + 6 * WB);
    float* bpr           = (float*)(ws + 2 * RB + 6 * WB + 2048);
    char* p = ws + 2 * RB + 6 * WB + 4096;
    int* ssrc    = (int*)p;
    int* offsets = ssrc + NE;
    int* pos     = offsets + NND + 2;
    int* bars    = pos + NND + 2;       // [0]=bar_cnt [1]=gtotal [2..7] pad
    int* counts  = bars + 8;            // contiguous with bars for one memset

    // zero barrier counter + segment cursor + histogram in ONE memset node
    hipMemsetAsync(bars, 0, (size_t)(8 + NND) * 4, stream);

    const float scf = 0.04419417382415922f;        // 1/sqrt(512)
    k_all<<<GRID, 256, 0, stream>>>(x, src, dst, Wq, bq, Wk, Wv, bv, Wo, bo, out,
                                    t, qh, WqTs, WkT, WvT, WoB, Amat, Wovb,
                                    bh, bpr, ssrc, offsets, pos, counts, bars, scf);
}

// Round 5
// 449.564 us; speedup vs baseline: 3.7140x; 1.7831x over previous
//
#include <hip/hip_runtime.h>
#include <math.h>
#include <stdint.h>

#define NND 20000
#define DIMK 512
#define NE  320000
#define GRID 1024

typedef __attribute__((ext_vector_type(8))) short short8;
typedef __attribute__((ext_vector_type(4))) float floatx4;

__device__ inline float bf2f(unsigned short h) {
    unsigned int u = ((unsigned int)h) << 16;
    return __uint_as_float(u);
}
__device__ inline unsigned short f2bf(float f) {
    unsigned int u = __float_as_uint(f);
    unsigned int r = (u + 0x7fffu + ((u >> 16) & 1u)) >> 16;
    return (unsigned short)r;
}

__device__ __forceinline__ void gld_lds16(const unsigned short* g, unsigned short* l) {
    __builtin_amdgcn_global_load_lds(
        (const __attribute__((address_space(1))) void*)g,
        (__attribute__((address_space(3))) void*)l,
        16, 0, 0);
}

// Broadcast grid barrier. R4 lesson: 1024 blocks polling ONE line with
// agent-scope (sc1, fabric) loads queues ~1.2G same-address reads/s against
// ~10s of M/s serialization capacity -> arrivals stall behind the poll
// backlog (~110us/barrier). Now: single fetch_add arrival, but the LAST
// arriver broadcasts to 1024 per-block flag lines (64B apart); each block
// polls only its private line (~1M polls/s/line -> no queueing). Fences as
// in R4 (proved correct): RELEASE (L2 wb) before arrival, ACQUIRE (L2 inv)
// after wake. cnt+flags zeroed by host memset each replay.
__device__ __forceinline__ void gbar(int* cnt, int* flags, int gen, char* smraw) {
    int* lastp = (int*)smraw;            // smem scratch (dead between phases)
    __syncthreads();
    if (threadIdx.x == 0) {
        __builtin_amdgcn_fence(__ATOMIC_RELEASE, "agent");
        int v = __hip_atomic_fetch_add(cnt, 1, __ATOMIC_RELAXED, __HIP_MEMORY_SCOPE_AGENT);
        *lastp = (v == gen * GRID + GRID - 1) ? 1 : 0;
    }
    __syncthreads();
    if (*lastp) {
        for (int b = threadIdx.x; b < GRID; b += 256)
            __hip_atomic_store(&flags[b * 16], gen + 1, __ATOMIC_RELAXED, __HIP_MEMORY_SCOPE_AGENT);
    } else if (threadIdx.x == 0) {
        while (__hip_atomic_load(&flags[blockIdx.x * 16], __ATOMIC_RELAXED, __HIP_MEMORY_SCOPE_AGENT) < gen + 1)
            __builtin_amdgcn_s_sleep(8);
    }
    __syncthreads();
    if (threadIdx.x == 0) __builtin_amdgcn_fence(__ATOMIC_ACQUIRE, "agent");
    __syncthreads();
}

// 128x128x512 bf16 GEMM tile (double-buffered, XOR-swizzled LDS), vb = tile id.
__device__ __forceinline__ void gemm_tile(int vb,
                                          const unsigned short* __restrict__ A,
                                          const unsigned short* __restrict__ B,
                                          const float* __restrict__ biasf,
                                          unsigned short* __restrict__ out_q,
                                          float* __restrict__ out_f,
                                          int M, int MT, int NT, int Ncols,
                                          unsigned short* smem) {
    int xcd = vb & 7, i = vb >> 3;
    int nt = i % NT, mt = (i / NT) * 8 + xcd;
    if (mt >= MT) return;
    int m0 = mt * 128, n0 = nt * 128;
    int tid = threadIdx.x, wv = tid >> 6, ln = tid & 63;
    int lr = ln & 15, qd = ln >> 4;
    int mh = wv >> 1, nh = wv & 1;

    floatx4 acc[4][4] = {};
    int srow = wv * 16 + (ln >> 2);
    int scol = (((ln & 3) ^ (ln >> 4)) & 3) * 8;
    int fsw = (qd ^ (lr >> 2)) & 3;

    {
        unsigned short* Ab = smem;
        unsigned short* Bb = smem + 8192;
#pragma unroll
        for (int p = 0; p < 2; p++) {
            int tr = p * 64 + srow;
            int ar = m0 + tr; if (ar > M - 1) ar = M - 1;
            gld_lds16(A + (size_t)ar * DIMK + scol, Ab + (p * 64 + wv * 16) * 32);
            gld_lds16(B + (size_t)(n0 + tr) * DIMK + scol, Bb + (p * 64 + wv * 16) * 32);
        }
    }

    for (int it = 0; it < 16; it++) {
        int cur = it & 1, nxt = cur ^ 1;
        __syncthreads();
        if (it + 1 < 16) {
            int kb = (it + 1) * 32;
            unsigned short* Ab = smem + nxt * 4096;
            unsigned short* Bb = smem + 8192 + nxt * 4096;
#pragma unroll
            for (int p = 0; p < 2; p++) {
                int tr = p * 64 + srow;
                int ar = m0 + tr; if (ar > M - 1) ar = M - 1;
                gld_lds16(A + (size_t)ar * DIMK + kb + scol, Ab + (p * 64 + wv * 16) * 32);
                gld_lds16(B + (size_t)(n0 + tr) * DIMK + kb + scol, Bb + (p * 64 + wv * 16) * 32);
            }
        }
        const unsigned short* Ac = smem + cur * 4096;
        const unsigned short* Bc = smem + 8192 + cur * 4096;
        short8 af[4], bfr[4];
#pragma unroll
        for (int mi = 0; mi < 4; mi++)
            af[mi] = *(const short8*)(Ac + (mh * 64 + mi * 16 + lr) * 32 + fsw * 8);
#pragma unroll
        for (int ni = 0; ni < 4; ni++)
            bfr[ni] = *(const short8*)(Bc + (nh * 64 + ni * 16 + lr) * 32 + fsw * 8);
#pragma unroll
        for (int mi = 0; mi < 4; mi++)
#pragma unroll
            for (int ni = 0; ni < 4; ni++)
                acc[mi][ni] = __builtin_amdgcn_mfma_f32_16x16x32_bf16(af[mi], bfr[ni], acc[mi][ni], 0, 0, 0);
    }

    float bb[4];
#pragma unroll
    for (int ni = 0; ni < 4; ni++) bb[ni] = biasf[n0 + nh * 64 + ni * 16 + lr];

    if (!out_f) {
        int col0 = nt * 128;
        unsigned short* cs = smem;
#pragma unroll
        for (int g = 0; g < 4; g++) {
            __syncthreads();
            if (mh == (g >> 1)) {
                int miB = (g & 1) * 2;
#pragma unroll
                for (int m2 = 0; m2 < 2; m2++) {
                    int mi = miB + m2;
                    int lrow = mi * 16 + qd * 4 - (g & 1) * 32;
#pragma unroll
                    for (int ni = 0; ni < 4; ni++) {
                        int col = nh * 64 + ni * 16 + lr;
#pragma unroll
                        for (int r = 0; r < 4; r++)
                            cs[(lrow + r) * 128 + col] = f2bf(acc[mi][ni][r] + bb[ni]);
                    }
                }
            }
            __syncthreads();
#pragma unroll
            for (int itr = 0; itr < 2; itr++) {
                int slot = itr * 256 + tid;
                int row = slot >> 4, cg = slot & 15;
                int gm = m0 + g * 32 + row;
                if (gm < M) {
                    short8 vv = *(const short8*)(cs + row * 128 + cg * 8);
                    *(short8*)(out_q + (size_t)gm * 512 + col0 + cg * 8) = vv;
                }
            }
        }
    } else {
#pragma unroll
        for (int ni = 0; ni < 4; ni++) {
            int gn = n0 + nh * 64 + ni * 16 + lr;
#pragma unroll
            for (int mi = 0; mi < 4; mi++) {
                int gm0 = m0 + mh * 64 + mi * 16 + qd * 4;
#pragma unroll
                for (int r = 0; r < 4; r++) {
                    int gm = gm0 + r;
                    if (gm < M) out_f[(size_t)gm * Ncols + gn] = acc[mi][ni][r] + bb[ni];
                }
            }
        }
    }
}

// ---------------- single persistent kernel: all phases ------------------------
__global__ __launch_bounds__(256, 4) void k_all(const float* __restrict__ x,
                                                const int* __restrict__ src,
                                                const int* __restrict__ dst,
                                                const float* __restrict__ Wq,
                                                const float* __restrict__ bq,
                                                const float* __restrict__ Wk,
                                                const float* __restrict__ Wv,
                                                const float* __restrict__ bv,
                                                const float* __restrict__ Wo,
                                                const float* __restrict__ bo,
                                                float* __restrict__ out,
                                                unsigned short* __restrict__ t,
                                                unsigned short* __restrict__ qh,
                                                unsigned short* __restrict__ WqTs,
                                                unsigned short* __restrict__ WkT,
                                                unsigned short* __restrict__ WvT,
                                                unsigned short* __restrict__ WoB,
                                                unsigned short* __restrict__ Amat,
                                                unsigned short* __restrict__ Wovb,
                                                float* __restrict__ bh,
                                                float* __restrict__ bpr,
                                                int* __restrict__ ssrc,
                                                int* __restrict__ offsets,
                                                int* __restrict__ pos,
                                                int* __restrict__ counts,
                                                int* __restrict__ bars,
                                                int* __restrict__ flags,
                                                float scf) {
    __shared__ __align__(16) char smraw[32768];
    unsigned short* smem = (unsigned short*)smraw;
    int tid = threadIdx.x;
    int* bar_cnt = bars;       // zeroed by host memset each replay
    int* gtotal  = bars + 1;   // zeroed by host memset each replay

    // ---- P0: logmap, weight cvt/transposes, bias folds, dst histogram ----
    for (int vb = blockIdx.x; vb < 6954; vb += GRID) {
        if (vb < 5000) {
            int row = vb * 4 + (tid >> 6);
            int lane = tid & 63;
            const floatx4* xp = (const floatx4*)(x + (size_t)row * DIMK + lane * 8);
            floatx4 x0 = xp[0], x1 = xp[1];
            float ss = 0.f;
#pragma unroll
            for (int i = 0; i < 4; i++) { ss += x0[i] * x0[i]; ss += x1[i] * x1[i]; }
#pragma unroll
            for (int off = 32; off >= 1; off >>= 1) ss += __shfl_xor(ss, off, 64);
            float n  = sqrtf(ss);
            float nc = fminf(fmaxf(n, 1e-7f), 1.0f - 1e-6f);
            float fac = atanhf(nc) / nc;
            union { short8 v; unsigned short u[8]; } o;
#pragma unroll
            for (int i = 0; i < 4; i++) { o.u[i] = f2bf(fac * x0[i]); o.u[4 + i] = f2bf(fac * x1[i]); }
            *(short8*)(t + (size_t)row * DIMK + lane * 8) = o.v;
        } else if (vb < 5256) {
            int i = (vb - 5000) * 256 + tid;
            floatx4 f = *(const floatx4*)(Wo + (size_t)i * 4);
            union { unsigned long long d; unsigned short u[4]; } o;
#pragma unroll
            for (int q = 0; q < 4; q++) o.u[q] = f2bf(f[q]);
            *(unsigned long long*)(WoB + (size_t)i * 4) = o.d;
        } else if (vb < 5448) {
            int g = vb - 5256;
            int m = g >> 6, tile = g & 63;
            int tr = tile >> 3, tc = tile & 7;
            const float* srcm = (m == 0) ? Wq : (m == 1) ? Wk : Wv;
            unsigned short* dstp = (m == 0) ? WqTs : (m == 1) ? WkT : WvT;
            float sc = (m == 0) ? scf : 1.0f;
            float (*tl)[65] = (float (*)[65])smraw;
            __syncthreads();
#pragma unroll
            for (int i = 0; i < 16; i++) {
                int idx = i * 256 + tid; int r = idx >> 6, c = idx & 63;
                tl[c][r] = srcm[(size_t)(tr * 64 + r) * 512 + tc * 64 + c];
            }
            __syncthreads();
#pragma unroll
            for (int i = 0; i < 16; i++) {
                int idx = i * 256 + tid; int r = idx >> 6, c = idx & 63;
                dstp[(size_t)(tc * 64 + r) * 512 + tr * 64 + c] = f2bf(tl[r][c] * sc);
            }
        } else if (vb < 5576) {
            int col = (vb - 5448) * 4 + (tid >> 6);
            int lane = tid & 63;
            int m0 = lane * 8;
            float s = 0.f;
#pragma unroll
            for (int j = 0; j < 8; j++) s += bq[m0 + j] * Wk[(size_t)(m0 + j) * 512 + col];
#pragma unroll
            for (int off = 32; off >= 1; off >>= 1) s += __shfl_xor(s, off, 64);
            if (lane == 0) bh[col] = s * scf;
        } else if (vb < 5704) {
            int row = (vb - 5576) * 4 + (tid >> 6);
            int lane = tid & 63;
            const floatx4* wp = (const floatx4*)(Wo + (size_t)row * 512 + lane * 8);
            const floatx4* bp = (const floatx4*)(bv + lane * 8);
            floatx4 a0 = wp[0], a1 = wp[1], c0 = bp[0], c1 = bp[1];
            float s = 0.f;
#pragma unroll
            for (int i = 0; i < 4; i++) { s += a0[i] * c0[i]; s += a1[i] * c1[i]; }
#pragma unroll
            for (int off = 32; off >= 1; off >>= 1) s += __shfl_xor(s, off, 64);
            if (lane == 0) bpr[row] = s + bo[row];
        } else {
            int e = (vb - 5704) * 256 + tid;
            if (e < NE) atomicAdd(&counts[dst[e]], 1);
        }
    }
    gbar(bar_cnt, flags, 0, smraw);

    // ---- P1: seg-alloc scan (vb<1000) + the two 512^3 weight products ----
    for (int vb = blockIdx.x; vb < 1032; vb += GRID) {
        if (vb < 1000) {
            if (tid < 64) {
                int lane = tid;
                int c = (lane < 20) ? counts[vb * 20 + lane] : 0;
                int p = c;
#pragma unroll
                for (int off = 1; off < 32; off <<= 1) {
                    int u = __shfl_up(p, off, 64);
                    if (lane >= off) p += u;
                }
                int excl = p - c;
                int btot = __shfl(p, 19, 64);
                int base;
                if (lane == 0) base = atomicAdd(gtotal, btot);
                base = __shfl(base, 0, 64);
                if (lane < 20) {
                    int o = base + excl;
                    offsets[vb * 20 + lane] = o;
                    pos[vb * 20 + lane] = o;
                }
            }
        } else {
            int g = vb - 1000;                   // 0..31
            int prod = g >> 4;
            int mt = (g >> 2) & 3, nt = g & 3;
            const unsigned short* A = prod ? WoB : WkT;
            const unsigned short* B = prod ? WvT : WqTs;
            unsigned short* outp = prod ? Wovb : Amat;
            int m0 = mt * 128, n0 = nt * 128;
            int wv = tid >> 6, ln = tid & 63;
            int lr = ln & 15, qd = ln >> 4;
            int mh = wv >> 1, nh = wv & 1;
            floatx4 acc[4][4] = {};
            int srow = wv * 16 + (ln >> 2);
            int scol = (((ln & 3) ^ (ln >> 4)) & 3) * 8;
            int fsw = (qd ^ (lr >> 2)) & 3;
            {
                unsigned short* Ab = smem;
                unsigned short* Bb = smem + 8192;
#pragma unroll
                for (int p = 0; p < 2; p++) {
                    int tr = p * 64 + srow;
                    gld_lds16(A + (size_t)(m0 + tr) * DIMK + scol, Ab + (p * 64 + wv * 16) * 32);
                    gld_lds16(B + (size_t)(n0 + tr) * DIMK + scol, Bb + (p * 64 + wv * 16) * 32);
                }
            }
            for (int it = 0; it < 16; it++) {
                int cur = it & 1, nxt = cur ^ 1;
                __syncthreads();
                if (it + 1 < 16) {
                    int kb = (it + 1) * 32;
                    unsigned short* Ab = smem + nxt * 4096;
                    unsigned short* Bb = smem + 8192 + nxt * 4096;
#pragma unroll
                    for (int p = 0; p < 2; p++) {
                        int tr = p * 64 + srow;
                        gld_lds16(A + (size_t)(m0 + tr) * DIMK + kb + scol, Ab + (p * 64 + wv * 16) * 32);
                        gld_lds16(B + (size_t)(n0 + tr) * DIMK + kb + scol, Bb + (p * 64 + wv * 16) * 32);
                    }
                }
                const unsigned short* Ac = smem + cur * 4096;
                const unsigned short* Bc = smem + 8192 + cur * 4096;
                short8 af[4], bfr[4];
#pragma unroll
                for (int mi = 0; mi < 4; mi++)
                    af[mi] = *(const short8*)(Ac + (mh * 64 + mi * 16 + lr) * 32 + fsw * 8);
#pragma unroll
                for (int ni = 0; ni < 4; ni++)
                    bfr[ni] = *(const short8*)(Bc + (nh * 64 + ni * 16 + lr) * 32 + fsw * 8);
#pragma unroll
                for (int mi = 0; mi < 4; mi++)
#pragma unroll
                    for (int ni = 0; ni < 4; ni++)
                        acc[mi][ni] = __builtin_amdgcn_mfma_f32_16x16x32_bf16(af[mi], bfr[ni], acc[mi][ni], 0, 0, 0);
            }
#pragma unroll
            for (int ni = 0; ni < 4; ni++) {
                int gn = n0 + nh * 64 + ni * 16 + lr;
#pragma unroll
                for (int mi = 0; mi < 4; mi++) {
                    int gm0 = m0 + mh * 64 + mi * 16 + qd * 4;
#pragma unroll
                    for (int r = 0; r < 4; r++)
                        outp[(size_t)(gm0 + r) * 512 + gn] = f2bf(acc[mi][ni][r]);
                }
            }
        }
    }
    gbar(bar_cnt, flags, 1, smraw);

    // ---- P2: qh GEMM (vb<640, needs Amat) + edge scatter (needs offsets) ----
    for (int vb = blockIdx.x; vb < 1890; vb += GRID) {
        if (vb < 640) {
            gemm_tile(vb, t, Amat, bh, qh, nullptr, NND, 157, 4, 512, smem);
        } else {
            int e = (vb - 640) * 256 + tid;
            if (e < NE) { int p = atomicAdd(&pos[dst[e]], 1); ssrc[p] = src[e]; }
        }
    }
    gbar(bar_cnt, flags, 2, smraw);

    // ---- P3: fused score+softmax+aggregate ----
    {
        float (*sacc)[512] = (float (*)[512])smraw;
        float* sden = (float*)(smraw + 4 * 512 * 4);
        int wv = tid >> 6, ln = tid & 63;
        for (int n = blockIdx.x; n < NND; n += GRID) {
            int beg = offsets[n], end = beg + counts[n];
            union { short8 v; unsigned short u[8]; } qu;
            qu.v = *(const short8*)(qh + (size_t)n * 512 + ln * 8);
            float qf[8];
#pragma unroll
            for (int j = 0; j < 8; j++) qf[j] = bf2f(qu.u[j]);
            float av[8] = {0, 0, 0, 0, 0, 0, 0, 0};
            float den = 0.f;
            int i = beg + wv * 2;
            for (; i + 1 < end; i += 8) {
                const unsigned short* p0 = t + (size_t)ssrc[i] * 512 + ln * 8;
                const unsigned short* p1 = t + (size_t)ssrc[i + 1] * 512 + ln * 8;
                union { short8 v; unsigned short u[8]; } r0, r1;
                r0.v = *(const short8*)p0;
                r1.v = *(const short8*)p1;
                float t0[8], t1[8];
                float d0 = 0.f, d1 = 0.f;
#pragma unroll
                for (int j = 0; j < 8; j++) {
                    t0[j] = bf2f(r0.u[j]); d0 += qf[j] * t0[j];
                    t1[j] = bf2f(r1.u[j]); d1 += qf[j] * t1[j];
                }
#pragma unroll
                for (int off = 32; off >= 1; off >>= 1) {
                    d0 += __shfl_xor(d0, off, 64);
                    d1 += __shfl_xor(d1, off, 64);
                }
                float w0 = __expf(d0), w1 = __expf(d1);
                den += w0 + w1;
#pragma unroll
                for (int j = 0; j < 8; j++) av[j] += w0 * t0[j] + w1 * t1[j];
            }
            if (i < end) {
                const unsigned short* p0 = t + (size_t)ssrc[i] * 512 + ln * 8;
                union { short8 v; unsigned short u[8]; } r0;
                r0.v = *(const short8*)p0;
                float t0[8];
                float d0 = 0.f;
#pragma unroll
                for (int j = 0; j < 8; j++) { t0[j] = bf2f(r0.u[j]); d0 += qf[j] * t0[j]; }
#pragma unroll
                for (int off = 32; off >= 1; off >>= 1) d0 += __shfl_xor(d0, off, 64);
                float w0 = __expf(d0);
                den += w0;
#pragma unroll
                for (int j = 0; j < 8; j++) av[j] += w0 * t0[j];
            }
            floatx4 s0v = {av[0], av[1], av[2], av[3]};
            floatx4 s1v = {av[4], av[5], av[6], av[7]};
            *(floatx4*)&sacc[wv][ln * 8]     = s0v;
            *(floatx4*)&sacc[wv][ln * 8 + 4] = s1v;
            if (ln == 0) sden[wv] = den;
            __syncthreads();
            float inv = 1.0f / (sden[0] + sden[1] + sden[2] + sden[3]);
            int c = tid * 2;
            float t0 = sacc[0][c] + sacc[1][c] + sacc[2][c] + sacc[3][c];
            float t1 = sacc[0][c + 1] + sacc[1][c + 1] + sacc[2][c + 1] + sacc[3][c + 1];
            qh[(size_t)n * 512 + c]     = f2bf(t0 * inv);   // attn aliases qh
            qh[(size_t)n * 512 + c + 1] = f2bf(t1 * inv);
            __syncthreads();
        }
    }
    gbar(bar_cnt, flags, 3, smraw);

    // ---- P4: out = attn @ Wovb^T + bpr (fp32) ----
    for (int vb = blockIdx.x; vb < 640; vb += GRID)
        gemm_tile(vb, qh, Wovb, bpr, nullptr, out, NND, 157, 4, 512, smem);
    gbar(bar_cnt, flags, 4, smraw);

    // ---- P5: expmap0 in place ----
    for (int vb = blockIdx.x; vb < 5000; vb += GRID) {
        int row = vb * 4 + (tid >> 6);
        int lane = tid & 63;
        floatx4* hp = (floatx4*)(out + (size_t)row * DIMK + lane * 8);
        floatx4 h0 = hp[0], h1 = hp[1];
        float ss = 0.f;
#pragma unroll
        for (int i = 0; i < 4; i++) { ss += h0[i] * h0[i]; ss += h1[i] * h1[i]; }
#pragma unroll
        for (int off = 32; off >= 1; off >>= 1) ss += __shfl_xor(ss, off, 64);
        float n  = sqrtf(ss);
        float nc = fmaxf(n, 1e-7f);
        float fac = tanhf(nc) / nc;
#pragma unroll
        for (int i = 0; i < 4; i++) { h0[i] *= fac; h1[i] *= fac; }
        hp[0] = h0; hp[1] = h1;
    }
}

extern "C" void kernel_launch(void* const* d_in, const int* in_sizes, int n_in,
                              void* d_out, int out_size, void* d_ws, size_t ws_size,
                              hipStream_t stream) {
    const float* x  = (const float*)d_in[0];
    const int* src  = (const int*)d_in[1];
    const int* dst  = (const int*)d_in[2];
    const float* Wq = (const float*)d_in[3];
    const float* bq = (const float*)d_in[4];
    const float* Wk = (const float*)d_in[5];
    const float* Wv = (const float*)d_in[7];
    const float* bv = (const float*)d_in[8];
    const float* Wo = (const float*)d_in[9];
    const float* bo = (const float*)d_in[10];
    float* out = (float*)d_out;

    char* ws = (char*)d_ws;
    const size_t RB  = (size_t)NND * DIMK * 2;     // 20.48 MB bf16 [N,512]
    const size_t WB  = (size_t)DIMK * DIMK * 2;    // 512 KB bf16 [512,512]
    unsigned short* t    = (unsigned short*)(ws);
    unsigned short* qh   = (unsigned short*)(ws + RB);      // attn aliases qh
    unsigned short* WqTs = (unsigned short*)(ws + 2 * RB);
    unsigned short* WkT  = (unsigned short*)(ws + 2 * RB + WB);
    unsigned short* WvT  = (unsigned short*)(ws + 2 * RB + 2 * WB);
    unsigned short* WoB  = (unsigned short*)(ws + 2 * RB + 3 * WB);
    unsigned short* Amat = (unsigned short*)(ws + 2 * RB + 4 * WB);
    unsigned short* Wovb = (unsigned short*)(ws + 2 * RB + 5 * WB);
    float* bh            = (float*)(ws + 2 * RB + 6 * WB);
    float* bpr           = (float*)(ws + 2 * RB + 6 * WB + 2048);
    char* p = ws + 2 * RB + 6 * WB + 4096;
    int* ssrc    = (int*)p;
    int* offsets = ssrc + NE;
    int* pos     = offsets + NND + 2;
    int* bars    = pos + NND + 2;       // [0]=bar_cnt [1]=gtotal [2..7] pad
    int* flags   = bars + 8;            // 1024 flags, 64B apart (16 ints)
    int* counts  = flags + GRID * 16;   // contiguous with bars for one memset

    // zero barrier counter + flags + segment cursor + histogram in ONE memset
    hipMemsetAsync(bars, 0, (size_t)(8 + GRID * 16 + NND) * 4, stream);

    const float scf = 0.04419417382415922f;        // 1/sqrt(512)
    k_all<<<GRID, 256, 0, stream>>>(x, src, dst, Wq, bq, Wk, Wv, bv, Wo, bo, out,
                                    t, qh, WqTs, WkT, WvT, WoB, Amat, Wovb,
                                    bh, bpr, ssrc, offsets, pos, counts, bars, flags, scf);
}

// Round 6
// 446.168 us; speedup vs baseline: 3.7423x; 1.0076x over previous
//
#include <hip/hip_runtime.h>
#include <math.h>
#include <stdint.h>

#define NND 20000
#define DIMK 512
#define NE  320000
#define GRID 1024

typedef __attribute__((ext_vector_type(8))) short short8;
typedef __attribute__((ext_vector_type(4))) float floatx4;

__device__ inline float bf2f(unsigned short h) {
    unsigned int u = ((unsigned int)h) << 16;
    return __uint_as_float(u);
}
__device__ inline unsigned short f2bf(float f) {
    unsigned int u = __float_as_uint(f);
    unsigned int r = (u + 0x7fffu + ((u >> 16) & 1u)) >> 16;
    return (unsigned short)r;
}

__device__ __forceinline__ void gld_lds16(const unsigned short* g, unsigned short* l) {
    __builtin_amdgcn_global_load_lds(
        (const __attribute__((address_space(1))) void*)g,
        (__attribute__((address_space(3))) void*)l,
        16, 0, 0);
}

// Grid barrier v3: NO same-line RMWs. R4/R5 lesson chain: (R4) 1024 blocks
// polling one line starves the line; (R5) 1024 fetch_adds on one line still
// serialize ~50ns-200ns each at the coherence point (~50us/barrier). Now:
// arrival = relaxed STORE to a private padded slot (1024 independent lines,
// fully parallel). Block 0 sweeps the slots (256 thr x 4), then broadcasts
// per-block wake flags (R5's proven wake path). Fences as validated in
// R4/R5: RELEASE (L2 wb) before arrival, ACQUIRE (L2 inv) after detection/
// wake. arr/wake zeroed by host memset each replay; gens are monotonic.
__device__ __forceinline__ void gbar(int gen1, int* arr, int* wake) {
    __syncthreads();
    if (blockIdx.x == 0) {
        if (threadIdx.x == 0) {
            __builtin_amdgcn_fence(__ATOMIC_RELEASE, "agent");
            __hip_atomic_store(&arr[0], gen1, __ATOMIC_RELAXED, __HIP_MEMORY_SCOPE_AGENT);
        }
        for (int b = threadIdx.x; b < GRID; b += 256)
            while (__hip_atomic_load(&arr[b * 16], __ATOMIC_RELAXED, __HIP_MEMORY_SCOPE_AGENT) < gen1)
                __builtin_amdgcn_s_sleep(2);
        __syncthreads();
        __builtin_amdgcn_fence(__ATOMIC_ACQUIRE, "agent");
        for (int b = threadIdx.x; b < GRID; b += 256)
            __hip_atomic_store(&wake[b * 16], gen1, __ATOMIC_RELAXED, __HIP_MEMORY_SCOPE_AGENT);
    } else {
        if (threadIdx.x == 0) {
            __builtin_amdgcn_fence(__ATOMIC_RELEASE, "agent");
            __hip_atomic_store(&arr[blockIdx.x * 16], gen1, __ATOMIC_RELAXED, __HIP_MEMORY_SCOPE_AGENT);
            while (__hip_atomic_load(&wake[blockIdx.x * 16], __ATOMIC_RELAXED, __HIP_MEMORY_SCOPE_AGENT) < gen1)
                __builtin_amdgcn_s_sleep(2);
            __builtin_amdgcn_fence(__ATOMIC_ACQUIRE, "agent");
        }
    }
    __syncthreads();
}

// 128x128x512 bf16 GEMM tile (double-buffered, XOR-swizzled LDS), vb = tile id.
__device__ __forceinline__ void gemm_tile(int vb,
                                          const unsigned short* __restrict__ A,
                                          const unsigned short* __restrict__ B,
                                          const float* __restrict__ biasf,
                                          unsigned short* __restrict__ out_q,
                                          float* __restrict__ out_f,
                                          int M, int MT, int NT, int Ncols,
                                          unsigned short* smem) {
    int xcd = vb & 7, i = vb >> 3;
    int nt = i % NT, mt = (i / NT) * 8 + xcd;
    if (mt >= MT) return;
    int m0 = mt * 128, n0 = nt * 128;
    int tid = threadIdx.x, wv = tid >> 6, ln = tid & 63;
    int lr = ln & 15, qd = ln >> 4;
    int mh = wv >> 1, nh = wv & 1;

    floatx4 acc[4][4] = {};
    int srow = wv * 16 + (ln >> 2);
    int scol = (((ln & 3) ^ (ln >> 4)) & 3) * 8;
    int fsw = (qd ^ (lr >> 2)) & 3;

    {
        unsigned short* Ab = smem;
        unsigned short* Bb = smem + 8192;
#pragma unroll
        for (int p = 0; p < 2; p++) {
            int tr = p * 64 + srow;
            int ar = m0 + tr; if (ar > M - 1) ar = M - 1;
            gld_lds16(A + (size_t)ar * DIMK + scol, Ab + (p * 64 + wv * 16) * 32);
            gld_lds16(B + (size_t)(n0 + tr) * DIMK + scol, Bb + (p * 64 + wv * 16) * 32);
        }
    }

    for (int it = 0; it < 16; it++) {
        int cur = it & 1, nxt = cur ^ 1;
        __syncthreads();
        if (it + 1 < 16) {
            int kb = (it + 1) * 32;
            unsigned short* Ab = smem + nxt * 4096;
            unsigned short* Bb = smem + 8192 + nxt * 4096;
#pragma unroll
            for (int p = 0; p < 2; p++) {
                int tr = p * 64 + srow;
                int ar = m0 + tr; if (ar > M - 1) ar = M - 1;
                gld_lds16(A + (size_t)ar * DIMK + kb + scol, Ab + (p * 64 + wv * 16) * 32);
                gld_lds16(B + (size_t)(n0 + tr) * DIMK + kb + scol, Bb + (p * 64 + wv * 16) * 32);
            }
        }
        const unsigned short* Ac = smem + cur * 4096;
        const unsigned short* Bc = smem + 8192 + cur * 4096;
        short8 af[4], bfr[4];
#pragma unroll
        for (int mi = 0; mi < 4; mi++)
            af[mi] = *(const short8*)(Ac + (mh * 64 + mi * 16 + lr) * 32 + fsw * 8);
#pragma unroll
        for (int ni = 0; ni < 4; ni++)
            bfr[ni] = *(const short8*)(Bc + (nh * 64 + ni * 16 + lr) * 32 + fsw * 8);
#pragma unroll
        for (int mi = 0; mi < 4; mi++)
#pragma unroll
            for (int ni = 0; ni < 4; ni++)
                acc[mi][ni] = __builtin_amdgcn_mfma_f32_16x16x32_bf16(af[mi], bfr[ni], acc[mi][ni], 0, 0, 0);
    }

    float bb[4];
#pragma unroll
    for (int ni = 0; ni < 4; ni++) bb[ni] = biasf[n0 + nh * 64 + ni * 16 + lr];

    if (!out_f) {
        int col0 = nt * 128;
        unsigned short* cs = smem;
#pragma unroll
        for (int g = 0; g < 4; g++) {
            __syncthreads();
            if (mh == (g >> 1)) {
                int miB = (g & 1) * 2;
#pragma unroll
                for (int m2 = 0; m2 < 2; m2++) {
                    int mi = miB + m2;
                    int lrow = mi * 16 + qd * 4 - (g & 1) * 32;
#pragma unroll
                    for (int ni = 0; ni < 4; ni++) {
                        int col = nh * 64 + ni * 16 + lr;
#pragma unroll
                        for (int r = 0; r < 4; r++)
                            cs[(lrow + r) * 128 + col] = f2bf(acc[mi][ni][r] + bb[ni]);
                    }
                }
            }
            __syncthreads();
#pragma unroll
            for (int itr = 0; itr < 2; itr++) {
                int slot = itr * 256 + tid;
                int row = slot >> 4, cg = slot & 15;
                int gm = m0 + g * 32 + row;
                if (gm < M) {
                    short8 vv = *(const short8*)(cs + row * 128 + cg * 8);
                    *(short8*)(out_q + (size_t)gm * 512 + col0 + cg * 8) = vv;
                }
            }
        }
    } else {
#pragma unroll
        for (int ni = 0; ni < 4; ni++) {
            int gn = n0 + nh * 64 + ni * 16 + lr;
#pragma unroll
            for (int mi = 0; mi < 4; mi++) {
                int gm0 = m0 + mh * 64 + mi * 16 + qd * 4;
#pragma unroll
                for (int r = 0; r < 4; r++) {
                    int gm = gm0 + r;
                    if (gm < M) out_f[(size_t)gm * Ncols + gn] = acc[mi][ni][r] + bb[ni];
                }
            }
        }
    }
}

// ---------------- single persistent kernel: all phases ------------------------
__global__ __launch_bounds__(256, 4) void k_all(const float* __restrict__ x,
                                                const int* __restrict__ src,
                                                const int* __restrict__ dst,
                                                const float* __restrict__ Wq,
                                                const float* __restrict__ bq,
                                                const float* __restrict__ Wk,
                                                const float* __restrict__ Wv,
                                                const float* __restrict__ bv,
                                                const float* __restrict__ Wo,
                                                const float* __restrict__ bo,
                                                float* __restrict__ out,
                                                unsigned short* __restrict__ t,
                                                unsigned short* __restrict__ qh,
                                                unsigned short* __restrict__ WqTs,
                                                unsigned short* __restrict__ WkT,
                                                unsigned short* __restrict__ WvT,
                                                unsigned short* __restrict__ WoB,
                                                unsigned short* __restrict__ Amat,
                                                unsigned short* __restrict__ Wovb,
                                                float* __restrict__ bh,
                                                float* __restrict__ bpr,
                                                int* __restrict__ ssrc,
                                                int* __restrict__ offsets,
                                                int* __restrict__ pos,
                                                int* __restrict__ counts,
                                                int* __restrict__ arr,
                                                int* __restrict__ wake,
                                                float scf) {
    __shared__ __align__(16) char smraw[32768];
    unsigned short* smem = (unsigned short*)smraw;
    int tid = threadIdx.x;

    // ---- P0: logmap, weight cvt/transposes, bias folds, dst histogram ----
    for (int vb = blockIdx.x; vb < 6954; vb += GRID) {
        if (vb < 5000) {
            int row = vb * 4 + (tid >> 6);
            int lane = tid & 63;
            const floatx4* xp = (const floatx4*)(x + (size_t)row * DIMK + lane * 8);
            floatx4 x0 = xp[0], x1 = xp[1];
            float ss = 0.f;
#pragma unroll
            for (int i = 0; i < 4; i++) { ss += x0[i] * x0[i]; ss += x1[i] * x1[i]; }
#pragma unroll
            for (int off = 32; off >= 1; off >>= 1) ss += __shfl_xor(ss, off, 64);
            float n  = sqrtf(ss);
            float nc = fminf(fmaxf(n, 1e-7f), 1.0f - 1e-6f);
            float fac = atanhf(nc) / nc;
            union { short8 v; unsigned short u[8]; } o;
#pragma unroll
            for (int i = 0; i < 4; i++) { o.u[i] = f2bf(fac * x0[i]); o.u[4 + i] = f2bf(fac * x1[i]); }
            *(short8*)(t + (size_t)row * DIMK + lane * 8) = o.v;
        } else if (vb < 5256) {
            int i = (vb - 5000) * 256 + tid;
            floatx4 f = *(const floatx4*)(Wo + (size_t)i * 4);
            union { unsigned long long d; unsigned short u[4]; } o;
#pragma unroll
            for (int q = 0; q < 4; q++) o.u[q] = f2bf(f[q]);
            *(unsigned long long*)(WoB + (size_t)i * 4) = o.d;
        } else if (vb < 5448) {
            int g = vb - 5256;
            int m = g >> 6, tile = g & 63;
            int tr = tile >> 3, tc = tile & 7;
            const float* srcm = (m == 0) ? Wq : (m == 1) ? Wk : Wv;
            unsigned short* dstp = (m == 0) ? WqTs : (m == 1) ? WkT : WvT;
            float sc = (m == 0) ? scf : 1.0f;
            float (*tl)[65] = (float (*)[65])smraw;
            __syncthreads();
#pragma unroll
            for (int i = 0; i < 16; i++) {
                int idx = i * 256 + tid; int r = idx >> 6, c = idx & 63;
                tl[c][r] = srcm[(size_t)(tr * 64 + r) * 512 + tc * 64 + c];
            }
            __syncthreads();
#pragma unroll
            for (int i = 0; i < 16; i++) {
                int idx = i * 256 + tid; int r = idx >> 6, c = idx & 63;
                dstp[(size_t)(tc * 64 + r) * 512 + tr * 64 + c] = f2bf(tl[r][c] * sc);
            }
        } else if (vb < 5576) {
            int col = (vb - 5448) * 4 + (tid >> 6);
            int lane = tid & 63;
            int m0 = lane * 8;
            float s = 0.f;
#pragma unroll
            for (int j = 0; j < 8; j++) s += bq[m0 + j] * Wk[(size_t)(m0 + j) * 512 + col];
#pragma unroll
            for (int off = 32; off >= 1; off >>= 1) s += __shfl_xor(s, off, 64);
            if (lane == 0) bh[col] = s * scf;
        } else if (vb < 5704) {
            int row = (vb - 5576) * 4 + (tid >> 6);
            int lane = tid & 63;
            const floatx4* wp = (const floatx4*)(Wo + (size_t)row * 512 + lane * 8);
            const floatx4* bp = (const floatx4*)(bv + lane * 8);
            floatx4 a0 = wp[0], a1 = wp[1], c0 = bp[0], c1 = bp[1];
            float s = 0.f;
#pragma unroll
            for (int i = 0; i < 4; i++) { s += a0[i] * c0[i]; s += a1[i] * c1[i]; }
#pragma unroll
            for (int off = 32; off >= 1; off >>= 1) s += __shfl_xor(s, off, 64);
            if (lane == 0) bpr[row] = s + bo[row];
        } else {
            int e = (vb - 5704) * 256 + tid;
            if (e < NE) atomicAdd(&counts[dst[e]], 1);
        }
    }
    gbar(1, arr, wake);

    // ---- P1: block 0 = full exclusive scan (no contended cursor);
    //          blocks 1..32 = the two 512^3 weight products ----
    if (blockIdx.x == 0) {
        const int CPT = 79;                          // 256*79 >= 20000
        int base = tid * CPT;
        int tot = 0;
        for (int i = 0; i < CPT; i++) {
            int idx = base + i;
            tot += (idx < NND) ? counts[idx] : 0;
        }
        int lane = tid & 63, w = tid >> 6;
        int v = tot;
#pragma unroll
        for (int off = 1; off < 64; off <<= 1) {
            int u = __shfl_up(v, off, 64);
            if (lane >= off) v += u;
        }
        int* wsum = (int*)smraw;
        if (lane == 63) wsum[w] = v;
        __syncthreads();
        int wbase = 0;
#pragma unroll
        for (int i = 0; i < 4; i++) wbase += (i < w) ? wsum[i] : 0;
        int run = wbase + (v - tot);
        for (int i = 0; i < CPT; i++) {
            int idx = base + i;
            if (idx < NND) {
                offsets[idx] = run; pos[idx] = run;
                run += counts[idx];
            }
        }
    } else if (blockIdx.x <= 32) {
        int g = blockIdx.x - 1;              // 0..31
        int prod = g >> 4;
        int mt = (g >> 2) & 3, nt = g & 3;
        const unsigned short* A = prod ? WoB : WkT;
        const unsigned short* B = prod ? WvT : WqTs;
        unsigned short* outp = prod ? Wovb : Amat;
        int m0 = mt * 128, n0 = nt * 128;
        int wv = tid >> 6, ln = tid & 63;
        int lr = ln & 15, qd = ln >> 4;
        int mh = wv >> 1, nh = wv & 1;
        floatx4 acc[4][4] = {};
        int srow = wv * 16 + (ln >> 2);
        int scol = (((ln & 3) ^ (ln >> 4)) & 3) * 8;
        int fsw = (qd ^ (lr >> 2)) & 3;
        {
            unsigned short* Ab = smem;
            unsigned short* Bb = smem + 8192;
#pragma unroll
            for (int p = 0; p < 2; p++) {
                int tr = p * 64 + srow;
                gld_lds16(A + (size_t)(m0 + tr) * DIMK + scol, Ab + (p * 64 + wv * 16) * 32);
                gld_lds16(B + (size_t)(n0 + tr) * DIMK + scol, Bb + (p * 64 + wv * 16) * 32);
            }
        }
        for (int it = 0; it < 16; it++) {
            int cur = it & 1, nxt = cur ^ 1;
            __syncthreads();
            if (it + 1 < 16) {
                int kb = (it + 1) * 32;
                unsigned short* Ab = smem + nxt * 4096;
                unsigned short* Bb = smem + 8192 + nxt * 4096;
#pragma unroll
                for (int p = 0; p < 2; p++) {
                    int tr = p * 64 + srow;
                    gld_lds16(A + (size_t)(m0 + tr) * DIMK + kb + scol, Ab + (p * 64 + wv * 16) * 32);
                    gld_lds16(B + (size_t)(n0 + tr) * DIMK + kb + scol, Bb + (p * 64 + wv * 16) * 32);
                }
            }
            const unsigned short* Ac = smem + cur * 4096;
            const unsigned short* Bc = smem + 8192 + cur * 4096;
            short8 af[4], bfr[4];
#pragma unroll
            for (int mi = 0; mi < 4; mi++)
                af[mi] = *(const short8*)(Ac + (mh * 64 + mi * 16 + lr) * 32 + fsw * 8);
#pragma unroll
            for (int ni = 0; ni < 4; ni++)
                bfr[ni] = *(const short8*)(Bc + (nh * 64 + ni * 16 + lr) * 32 + fsw * 8);
#pragma unroll
            for (int mi = 0; mi < 4; mi++)
#pragma unroll
                for (int ni = 0; ni < 4; ni++)
                    acc[mi][ni] = __builtin_amdgcn_mfma_f32_16x16x32_bf16(af[mi], bfr[ni], acc[mi][ni], 0, 0, 0);
        }
#pragma unroll
        for (int ni = 0; ni < 4; ni++) {
            int gn = n0 + nh * 64 + ni * 16 + lr;
#pragma unroll
            for (int mi = 0; mi < 4; mi++) {
                int gm0 = m0 + mh * 64 + mi * 16 + qd * 4;
#pragma unroll
                for (int r = 0; r < 4; r++)
                    outp[(size_t)(gm0 + r) * 512 + gn] = f2bf(acc[mi][ni][r]);
            }
        }
    }
    gbar(2, arr, wake);

    // ---- P2: scatter on blocks [0,384) (light; block 0 = early detector);
    //          qh GEMM tiles on blocks [384,1024) ----
    if (blockIdx.x < 384) {
#pragma unroll
        for (int k = 0; k < 4; k++) {
            int chunk = blockIdx.x + k * 384;
            if (chunk < 1250) {
                int e = chunk * 256 + tid;
                if (e < NE) { int p = atomicAdd(&pos[dst[e]], 1); ssrc[p] = src[e]; }
            }
        }
    } else {
        gemm_tile(blockIdx.x - 384, t, Amat, bh, qh, nullptr, NND, 157, 4, 512, smem);
    }
    gbar(3, arr, wake);

    // ---- P3: fused score+softmax+aggregate ----
    {
        float (*sacc)[512] = (float (*)[512])smraw;
        float* sden = (float*)(smraw + 4 * 512 * 4);
        int wv = tid >> 6, ln = tid & 63;
        for (int n = blockIdx.x; n < NND; n += GRID) {
            int beg = offsets[n], end = beg + counts[n];
            union { short8 v; unsigned short u[8]; } qu;
            qu.v = *(const short8*)(qh + (size_t)n * 512 + ln * 8);
            float qf[8];
#pragma unroll
            for (int j = 0; j < 8; j++) qf[j] = bf2f(qu.u[j]);
            float av[8] = {0, 0, 0, 0, 0, 0, 0, 0};
            float den = 0.f;
            int i = beg + wv * 2;
            for (; i + 1 < end; i += 8) {
                const unsigned short* p0 = t + (size_t)ssrc[i] * 512 + ln * 8;
                const unsigned short* p1 = t + (size_t)ssrc[i + 1] * 512 + ln * 8;
                union { short8 v; unsigned short u[8]; } r0, r1;
                r0.v = *(const short8*)p0;
                r1.v = *(const short8*)p1;
                float t0[8], t1[8];
                float d0 = 0.f, d1 = 0.f;
#pragma unroll
                for (int j = 0; j < 8; j++) {
                    t0[j] = bf2f(r0.u[j]); d0 += qf[j] * t0[j];
                    t1[j] = bf2f(r1.u[j]); d1 += qf[j] * t1[j];
                }
#pragma unroll
                for (int off = 32; off >= 1; off >>= 1) {
                    d0 += __shfl_xor(d0, off, 64);
                    d1 += __shfl_xor(d1, off, 64);
                }
                float w0 = __expf(d0), w1 = __expf(d1);
                den += w0 + w1;
#pragma unroll
                for (int j = 0; j < 8; j++) av[j] += w0 * t0[j] + w1 * t1[j];
            }
            if (i < end) {
                const unsigned short* p0 = t + (size_t)ssrc[i] * 512 + ln * 8;
                union { short8 v; unsigned short u[8]; } r0;
                r0.v = *(const short8*)p0;
                float t0[8];
                float d0 = 0.f;
#pragma unroll
                for (int j = 0; j < 8; j++) { t0[j] = bf2f(r0.u[j]); d0 += qf[j] * t0[j]; }
#pragma unroll
                for (int off = 32; off >= 1; off >>= 1) d0 += __shfl_xor(d0, off, 64);
                float w0 = __expf(d0);
                den += w0;
#pragma unroll
                for (int j = 0; j < 8; j++) av[j] += w0 * t0[j];
            }
            floatx4 s0v = {av[0], av[1], av[2], av[3]};
            floatx4 s1v = {av[4], av[5], av[6], av[7]};
            *(floatx4*)&sacc[wv][ln * 8]     = s0v;
            *(floatx4*)&sacc[wv][ln * 8 + 4] = s1v;
            if (ln == 0) sden[wv] = den;
            __syncthreads();
            float inv = 1.0f / (sden[0] + sden[1] + sden[2] + sden[3]);
            int c = tid * 2;
            float t0 = sacc[0][c] + sacc[1][c] + sacc[2][c] + sacc[3][c];
            float t1 = sacc[0][c + 1] + sacc[1][c + 1] + sacc[2][c + 1] + sacc[3][c + 1];
            qh[(size_t)n * 512 + c]     = f2bf(t0 * inv);   // attn aliases qh
            qh[(size_t)n * 512 + c + 1] = f2bf(t1 * inv);
            __syncthreads();
        }
    }
    gbar(4, arr, wake);

    // ---- P4: out = attn @ Wovb^T + bpr (fp32) ----
    for (int vb = blockIdx.x; vb < 640; vb += GRID)
        gemm_tile(vb, qh, Wovb, bpr, nullptr, out, NND, 157, 4, 512, smem);
    gbar(5, arr, wake);

    // ---- P5: expmap0 in place ----
    for (int vb = blockIdx.x; vb < 5000; vb += GRID) {
        int row = vb * 4 + (tid >> 6);
        int lane = tid & 63;
        floatx4* hp = (floatx4*)(out + (size_t)row * DIMK + lane * 8);
        floatx4 h0 = hp[0], h1 = hp[1];
        float ss = 0.f;
#pragma unroll
        for (int i = 0; i < 4; i++) { ss += h0[i] * h0[i]; ss += h1[i] * h1[i]; }
#pragma unroll
        for (int off = 32; off >= 1; off >>= 1) ss += __shfl_xor(ss, off, 64);
        float n  = sqrtf(ss);
        float nc = fmaxf(n, 1e-7f);
        float fac = tanhf(nc) / nc;
#pragma unroll
        for (int i = 0; i < 4; i++) { h0[i] *= fac; h1[i] *= fac; }
        hp[0] = h0; hp[1] = h1;
    }
}

extern "C" void kernel_launch(void* const* d_in, const int* in_sizes, int n_in,
                              void* d_out, int out_size, void* d_ws, size_t ws_size,
                              hipStream_t stream) {
    const float* x  = (const float*)d_in[0];
    const int* src  = (const int*)d_in[1];
    const int* dst  = (const int*)d_in[2];
    const float* Wq = (const float*)d_in[3];
    const float* bq = (const float*)d_in[4];
    const float* Wk = (const float*)d_in[5];
    const float* Wv = (const float*)d_in[7];
    const float* bv = (const float*)d_in[8];
    const float* Wo = (const float*)d_in[9];
    const float* bo = (const float*)d_in[10];
    float* out = (float*)d_out;

    char* ws = (char*)d_ws;
    const size_t RB  = (size_t)NND * DIMK * 2;     // 20.48 MB bf16 [N,512]
    const size_t WB  = (size_t)DIMK * DIMK * 2;    // 512 KB bf16 [512,512]
    unsigned short* t    = (unsigned short*)(ws);
    unsigned short* qh   = (unsigned short*)(ws + RB);      // attn aliases qh
    unsigned short* WqTs = (unsigned short*)(ws + 2 * RB);
    unsigned short* WkT  = (unsigned short*)(ws + 2 * RB + WB);
    unsigned short* WvT  = (unsigned short*)(ws + 2 * RB + 2 * WB);
    unsigned short* WoB  = (unsigned short*)(ws + 2 * RB + 3 * WB);
    unsigned short* Amat = (unsigned short*)(ws + 2 * RB + 4 * WB);
    unsigned short* Wovb = (unsigned short*)(ws + 2 * RB + 5 * WB);
    float* bh            = (float*)(ws + 2 * RB + 6 * WB);
    float* bpr           = (float*)(ws + 2 * RB + 6 * WB + 2048);
    char* p = ws + 2 * RB + 6 * WB + 4096;
    int* ssrc    = (int*)p;
    int* offsets = ssrc + NE;
    int* pos     = offsets + NND + 2;
    int* arr     = pos + NND + 2;       // 1024 arrival slots, 64B apart
    int* wake    = arr + GRID * 16;     // 1024 wake flags, 64B apart
    int* counts  = wake + GRID * 16;    // contiguous -> one memset

    // zero arrival slots + wake flags + histogram in ONE memset node
    hipMemsetAsync(arr, 0, (size_t)(GRID * 16 * 2 + NND) * 4, stream);

    const float scf = 0.04419417382415922f;        // 1/sqrt(512)
    k_all<<<GRID, 256, 0, stream>>>(x, src, dst, Wq, bq, Wk, Wv, bv, Wo, bo, out,
                                    t, qh, WqTs, WkT, WvT, WoB, Amat, Wovb,
                                    bh, bpr, ssrc, offsets, pos, counts, arr, wake, scf);
}

// Round 7
// 345.895 us; speedup vs baseline: 4.8271x; 1.2899x over previous
//
#include <hip/hip_runtime.h>
#include <math.h>
#include <stdint.h>

#define NND 20000
#define DIMK 512
#define NE  320000

typedef __attribute__((ext_vector_type(8))) short short8;
typedef __attribute__((ext_vector_type(4))) float floatx4;
typedef __attribute__((ext_vector_type(2))) float float2v;

__device__ inline float bf2f(unsigned short h) {
    unsigned int u = ((unsigned int)h) << 16;
    return __uint_as_float(u);
}
__device__ inline unsigned short f2bf(float f) {
    unsigned int u = __float_as_uint(f);
    unsigned int r = (u + 0x7fffu + ((u >> 16) & 1u)) >> 16;
    return (unsigned short)r;
}
// unpack one u32 (2 bf16) -> float2 {elem0, elem1}
__device__ __forceinline__ float2v up2(unsigned int u) {
    float2v r;
    r.x = __uint_as_float(u << 16);
    r.y = __uint_as_float(u & 0xFFFF0000u);
    return r;
}

__device__ __forceinline__ void gld_lds16(const unsigned short* g, unsigned short* l) {
    __builtin_amdgcn_global_load_lds(
        (const __attribute__((address_space(1))) void*)g,
        (__attribute__((address_space(3))) void*)l,
        16, 0, 0);
}

// ---------------- fused pre-pass (R2-verified, verbatim) ----------------------
// blocks: [0,5000) logmap -> t bf16; [5000,5256) WoB cvt; [5256,5448) transposes
// (WqTs scaled); [5448,5450) bh; [5450,5578) bpr; [5578,6828) dst histogram
__global__ __launch_bounds__(256) void k_pre(const float* __restrict__ x,
                                             const float* __restrict__ Wq,
                                             const float* __restrict__ Wk,
                                             const float* __restrict__ Wv,
                                             const float* __restrict__ Wo,
                                             const float* __restrict__ bq,
                                             const float* __restrict__ bv,
                                             const float* __restrict__ bo,
                                             const int* __restrict__ dst,
                                             int* __restrict__ counts,
                                             unsigned short* __restrict__ t,
                                             unsigned short* __restrict__ WqTs,
                                             unsigned short* __restrict__ WkT,
                                             unsigned short* __restrict__ WvT,
                                             unsigned short* __restrict__ WoB,
                                             float* __restrict__ bh,
                                             float* __restrict__ bpr,
                                             float scf) {
    int blk = blockIdx.x, tid = threadIdx.x;
    if (blk < 5000) {
        int row = blk * 4 + (tid >> 6);
        int lane = tid & 63;
        const floatx4* xp = (const floatx4*)(x + (size_t)row * DIMK + lane * 8);
        floatx4 x0 = xp[0], x1 = xp[1];
        float ss = 0.f;
#pragma unroll
        for (int i = 0; i < 4; i++) { ss += x0[i] * x0[i]; ss += x1[i] * x1[i]; }
#pragma unroll
        for (int off = 32; off >= 1; off >>= 1) ss += __shfl_xor(ss, off, 64);
        float n  = sqrtf(ss);
        float nc = fminf(fmaxf(n, 1e-7f), 1.0f - 1e-6f);
        float fac = atanhf(nc) / nc;
        union { short8 v; unsigned short u[8]; } o;
#pragma unroll
        for (int i = 0; i < 4; i++) { o.u[i] = f2bf(fac * x0[i]); o.u[4 + i] = f2bf(fac * x1[i]); }
        *(short8*)(t + (size_t)row * DIMK + lane * 8) = o.v;
    } else if (blk < 5256) {
        int i = (blk - 5000) * 256 + tid;
        floatx4 f = *(const floatx4*)(Wo + (size_t)i * 4);
        union { unsigned long long d; unsigned short u[4]; } o;
#pragma unroll
        for (int q = 0; q < 4; q++) o.u[q] = f2bf(f[q]);
        *(unsigned long long*)(WoB + (size_t)i * 4) = o.d;
    } else if (blk < 5448) {
        int g = blk - 5256;
        int m = g >> 6, tile = g & 63;
        int tr = tile >> 3, tc = tile & 7;
        const float* srcm = (m == 0) ? Wq : (m == 1) ? Wk : Wv;
        unsigned short* dstp = (m == 0) ? WqTs : (m == 1) ? WkT : WvT;
        float sc = (m == 0) ? scf : 1.0f;
        __shared__ float tl[64][65];
#pragma unroll
        for (int i = 0; i < 16; i++) {
            int idx = i * 256 + tid; int r = idx >> 6, c = idx & 63;
            tl[c][r] = srcm[(size_t)(tr * 64 + r) * 512 + tc * 64 + c];
        }
        __syncthreads();
#pragma unroll
        for (int i = 0; i < 16; i++) {
            int idx = i * 256 + tid; int r = idx >> 6, c = idx & 63;
            dstp[(size_t)(tc * 64 + r) * 512 + tr * 64 + c] = f2bf(tl[r][c] * sc);
        }
    } else if (blk < 5450) {
        int col = (blk - 5448) * 256 + tid;
        float s = 0.f;
#pragma unroll 8
        for (int m = 0; m < 512; m++) s += bq[m] * Wk[(size_t)m * 512 + col];
        bh[col] = s * scf;
    } else if (blk < 5578) {
        int row = (blk - 5450) * 4 + (tid >> 6);
        int lane = tid & 63;
        const floatx4* wp = (const floatx4*)(Wo + (size_t)row * 512 + lane * 8);
        const floatx4* bp = (const floatx4*)(bv + lane * 8);
        floatx4 a0 = wp[0], a1 = wp[1], c0 = bp[0], c1 = bp[1];
        float s = 0.f;
#pragma unroll
        for (int i = 0; i < 4; i++) { s += a0[i] * c0[i]; s += a1[i] * c1[i]; }
#pragma unroll
        for (int off = 32; off >= 1; off >>= 1) s += __shfl_xor(s, off, 64);
        if (lane == 0) bpr[row] = s + bo[row];
    } else {
        int e = (blk - 5578) * 256 + tid;
        if (e < NE) atomicAdd(&counts[dst[e]], 1);
    }
}

// ---------------- 128x128x512 GEMM tile (R2-verified), device function --------
__device__ __forceinline__ void gemm_tile(int vb,
                                          const unsigned short* __restrict__ A,
                                          const unsigned short* __restrict__ B,
                                          const float* __restrict__ biasf,
                                          unsigned short* __restrict__ out_q,
                                          float* __restrict__ out_f,
                                          int M, int MT, int NT, int Ncols,
                                          unsigned short* smem) {
    int xcd = vb & 7, i = vb >> 3;
    int nt = i % NT, mt = (i / NT) * 8 + xcd;
    if (mt >= MT) return;
    int m0 = mt * 128, n0 = nt * 128;
    int tid = threadIdx.x, wv = tid >> 6, ln = tid & 63;
    int lr = ln & 15, qd = ln >> 4;
    int mh = wv >> 1, nh = wv & 1;

    floatx4 acc[4][4] = {};
    int srow = wv * 16 + (ln >> 2);
    int scol = (((ln & 3) ^ (ln >> 4)) & 3) * 8;
    int fsw = (qd ^ (lr >> 2)) & 3;

    {
        unsigned short* Ab = smem;
        unsigned short* Bb = smem + 8192;
#pragma unroll
        for (int p = 0; p < 2; p++) {
            int tr = p * 64 + srow;
            int ar = m0 + tr; if (ar > M - 1) ar = M - 1;
            gld_lds16(A + (size_t)ar * DIMK + scol, Ab + (p * 64 + wv * 16) * 32);
            gld_lds16(B + (size_t)(n0 + tr) * DIMK + scol, Bb + (p * 64 + wv * 16) * 32);
        }
    }

    for (int it = 0; it < 16; it++) {
        int cur = it & 1, nxt = cur ^ 1;
        __syncthreads();
        if (it + 1 < 16) {
            int kb = (it + 1) * 32;
            unsigned short* Ab = smem + nxt * 4096;
            unsigned short* Bb = smem + 8192 + nxt * 4096;
#pragma unroll
            for (int p = 0; p < 2; p++) {
                int tr = p * 64 + srow;
                int ar = m0 + tr; if (ar > M - 1) ar = M - 1;
                gld_lds16(A + (size_t)ar * DIMK + kb + scol, Ab + (p * 64 + wv * 16) * 32);
                gld_lds16(B + (size_t)(n0 + tr) * DIMK + kb + scol, Bb + (p * 64 + wv * 16) * 32);
            }
        }
        const unsigned short* Ac = smem + cur * 4096;
        const unsigned short* Bc = smem + 8192 + cur * 4096;
        short8 af[4], bfr[4];
#pragma unroll
        for (int mi = 0; mi < 4; mi++)
            af[mi] = *(const short8*)(Ac + (mh * 64 + mi * 16 + lr) * 32 + fsw * 8);
#pragma unroll
        for (int ni = 0; ni < 4; ni++)
            bfr[ni] = *(const short8*)(Bc + (nh * 64 + ni * 16 + lr) * 32 + fsw * 8);
#pragma unroll
        for (int mi = 0; mi < 4; mi++)
#pragma unroll
            for (int ni = 0; ni < 4; ni++)
                acc[mi][ni] = __builtin_amdgcn_mfma_f32_16x16x32_bf16(af[mi], bfr[ni], acc[mi][ni], 0, 0, 0);
    }

    float bb[4];
#pragma unroll
    for (int ni = 0; ni < 4; ni++) bb[ni] = biasf[n0 + nh * 64 + ni * 16 + lr];

    if (!out_f) {
        int col0 = nt * 128;
        unsigned short* cs = smem;
#pragma unroll
        for (int g = 0; g < 4; g++) {
            __syncthreads();
            if (mh == (g >> 1)) {
                int miB = (g & 1) * 2;
#pragma unroll
                for (int m2 = 0; m2 < 2; m2++) {
                    int mi = miB + m2;
                    int lrow = mi * 16 + qd * 4 - (g & 1) * 32;
#pragma unroll
                    for (int ni = 0; ni < 4; ni++) {
                        int col = nh * 64 + ni * 16 + lr;
#pragma unroll
                        for (int r = 0; r < 4; r++)
                            cs[(lrow + r) * 128 + col] = f2bf(acc[mi][ni][r] + bb[ni]);
                    }
                }
            }
            __syncthreads();
#pragma unroll
            for (int itr = 0; itr < 2; itr++) {
                int slot = itr * 256 + tid;
                int row = slot >> 4, cg = slot & 15;
                int gm = m0 + g * 32 + row;
                if (gm < M) {
                    short8 vv = *(const short8*)(cs + row * 128 + cg * 8);
                    *(short8*)(out_q + (size_t)gm * 512 + col0 + cg * 8) = vv;
                }
            }
        }
    } else {
#pragma unroll
        for (int ni = 0; ni < 4; ni++) {
            int gn = n0 + nh * 64 + ni * 16 + lr;
#pragma unroll
            for (int mi = 0; mi < 4; mi++) {
                int gm0 = m0 + mh * 64 + mi * 16 + qd * 4;
#pragma unroll
                for (int r = 0; r < 4; r++) {
                    int gm = gm0 + r;
                    if (gm < M) out_f[(size_t)gm * Ncols + gn] = acc[mi][ni][r] + bb[ni];
                }
            }
        }
    }
}

// ---------------- scan (block 0) + the two 512^3 weight products (blocks 1-32)
__global__ __launch_bounds__(256) void k_scan33(const int* __restrict__ counts,
                                                int* __restrict__ offsets,
                                                int* __restrict__ pos,
                                                const unsigned short* __restrict__ WkT,
                                                const unsigned short* __restrict__ WqTs,
                                                const unsigned short* __restrict__ WoB,
                                                const unsigned short* __restrict__ WvT,
                                                unsigned short* __restrict__ Amat,
                                                unsigned short* __restrict__ Wovb) {
    __shared__ unsigned short smem[16384];
    int tid = threadIdx.x;
    if (blockIdx.x == 0) {
        // 256-thread exclusive scan of counts[20000] (R6-verified)
        const int CPT = 79;
        int base = tid * CPT;
        int tot = 0;
        for (int i = 0; i < CPT; i++) {
            int idx = base + i;
            tot += (idx < NND) ? counts[idx] : 0;
        }
        int lane = tid & 63, w = tid >> 6;
        int v = tot;
#pragma unroll
        for (int off = 1; off < 64; off <<= 1) {
            int u = __shfl_up(v, off, 64);
            if (lane >= off) v += u;
        }
        int* wsum = (int*)smem;
        if (lane == 63) wsum[w] = v;
        __syncthreads();
        int wbase = 0;
#pragma unroll
        for (int i = 0; i < 4; i++) wbase += (i < w) ? wsum[i] : 0;
        int run = wbase + (v - tot);
        for (int i = 0; i < CPT; i++) {
            int idx = base + i;
            if (idx < NND) {
                offsets[idx] = run; pos[idx] = run;
                run += counts[idx];
            }
        }
        return;
    }
    int g = blockIdx.x - 1;              // 0..31
    int prod = g >> 4;
    int mt = (g >> 2) & 3, nt = g & 3;
    const unsigned short* A = prod ? WoB : WkT;
    const unsigned short* B = prod ? WvT : WqTs;
    unsigned short* outp = prod ? Wovb : Amat;
    int m0 = mt * 128, n0 = nt * 128;
    int wv = tid >> 6, ln = tid & 63;
    int lr = ln & 15, qd = ln >> 4;
    int mh = wv >> 1, nh = wv & 1;
    floatx4 acc[4][4] = {};
    int srow = wv * 16 + (ln >> 2);
    int scol = (((ln & 3) ^ (ln >> 4)) & 3) * 8;
    int fsw = (qd ^ (lr >> 2)) & 3;
    {
        unsigned short* Ab = smem;
        unsigned short* Bb = smem + 8192;
#pragma unroll
        for (int p = 0; p < 2; p++) {
            int tr = p * 64 + srow;
            gld_lds16(A + (size_t)(m0 + tr) * DIMK + scol, Ab + (p * 64 + wv * 16) * 32);
            gld_lds16(B + (size_t)(n0 + tr) * DIMK + scol, Bb + (p * 64 + wv * 16) * 32);
        }
    }
    for (int it = 0; it < 16; it++) {
        int cur = it & 1, nxt = cur ^ 1;
        __syncthreads();
        if (it + 1 < 16) {
            int kb = (it + 1) * 32;
            unsigned short* Ab = smem + nxt * 4096;
            unsigned short* Bb = smem + 8192 + nxt * 4096;
#pragma unroll
            for (int p = 0; p < 2; p++) {
                int tr = p * 64 + srow;
                gld_lds16(A + (size_t)(m0 + tr) * DIMK + kb + scol, Ab + (p * 64 + wv * 16) * 32);
                gld_lds16(B + (size_t)(n0 + tr) * DIMK + kb + scol, Bb + (p * 64 + wv * 16) * 32);
            }
        }
        const unsigned short* Ac = smem + cur * 4096;
        const unsigned short* Bc = smem + 8192 + cur * 4096;
        short8 af[4], bfr[4];
#pragma unroll
        for (int mi = 0; mi < 4; mi++)
            af[mi] = *(const short8*)(Ac + (mh * 64 + mi * 16 + lr) * 32 + fsw * 8);
#pragma unroll
        for (int ni = 0; ni < 4; ni++)
            bfr[ni] = *(const short8*)(Bc + (nh * 64 + ni * 16 + lr) * 32 + fsw * 8);
#pragma unroll
        for (int mi = 0; mi < 4; mi++)
#pragma unroll
            for (int ni = 0; ni < 4; ni++)
                acc[mi][ni] = __builtin_amdgcn_mfma_f32_16x16x32_bf16(af[mi], bfr[ni], acc[mi][ni], 0, 0, 0);
    }
#pragma unroll
    for (int ni = 0; ni < 4; ni++) {
        int gn = n0 + nh * 64 + ni * 16 + lr;
#pragma unroll
        for (int mi = 0; mi < 4; mi++) {
            int gm0 = m0 + mh * 64 + mi * 16 + qd * 4;
#pragma unroll
            for (int r = 0; r < 4; r++)
                outp[(size_t)(gm0 + r) * 512 + gn] = f2bf(acc[mi][ni][r]);
        }
    }
}

// ---------------- merged: qh GEMM (blocks <640) + edge scatter (rest) ---------
__global__ __launch_bounds__(256) void k_sg(const unsigned short* __restrict__ t,
                                            const unsigned short* __restrict__ Amat,
                                            const float* __restrict__ bh,
                                            unsigned short* __restrict__ qh,
                                            const int* __restrict__ dst,
                                            const int* __restrict__ src,
                                            int* __restrict__ pos,
                                            int* __restrict__ ssrc) {
    __shared__ unsigned short smem[16384];
    int b = blockIdx.x;
    if (b < 640) {
        gemm_tile(b, t, Amat, bh, qh, nullptr, NND, 157, 4, 512, smem);
    } else {
        int e = (b - 640) * 256 + threadIdx.x;
        if (e < NE) { int p = atomicAdd(&pos[dst[e]], 1); ssrc[p] = src[e]; }
    }
}

// ---------------- proj GEMM (fp32 out) ----------------------------------------
__global__ __launch_bounds__(256) void k_proj(const unsigned short* __restrict__ A,
                                              const unsigned short* __restrict__ B,
                                              const float* __restrict__ biasf,
                                              float* __restrict__ out_f) {
    __shared__ unsigned short smem[16384];
    gemm_tile(blockIdx.x, A, B, biasf, nullptr, out_f, NND, 157, 4, 512, smem);
}

// ---------------- fused score+softmax+aggregate (16-lane-group per edge) ------
// Each 16-lane group owns one edge at a time (slot = wave*4+grp, stride 16).
// Lane owns 32 dims (64B contiguous load). 4-level butterfly for the dot
// (vs 6 before); w needs no broadcast; float2v math -> v_pk_fma_f32.
// Transposed [4][32][17] LDS layout keeps the final reduce conflict-free.
__global__ __launch_bounds__(256) void k_fsa(const int* __restrict__ offsets,
                                             const int* __restrict__ counts,
                                             const int* __restrict__ ssrc,
                                             const unsigned short* __restrict__ qb,
                                             const unsigned short* __restrict__ tb,
                                             unsigned short* __restrict__ attn) {
    __shared__ float sacc[4][32][17];
    __shared__ float sden[4];
    int n = blockIdx.x, tid = threadIdx.x;
    int wv = tid >> 6, ln = tid & 63;
    int grp = ln >> 4, li = ln & 15;
    int slot = wv * 4 + grp;                         // 0..15
    int beg = offsets[n], end = beg + counts[n];

    const uint4* qp = (const uint4*)(qb + (size_t)n * 512 + li * 32);
    uint4 qa = qp[0], qb4 = qp[1], qc = qp[2], qd4 = qp[3];
    float2v q2[16];
    q2[0] = up2(qa.x);  q2[1] = up2(qa.y);  q2[2] = up2(qa.z);  q2[3] = up2(qa.w);
    q2[4] = up2(qb4.x); q2[5] = up2(qb4.y); q2[6] = up2(qb4.z); q2[7] = up2(qb4.w);
    q2[8] = up2(qc.x);  q2[9] = up2(qc.y);  q2[10] = up2(qc.z); q2[11] = up2(qc.w);
    q2[12] = up2(qd4.x); q2[13] = up2(qd4.y); q2[14] = up2(qd4.z); q2[15] = up2(qd4.w);

    float2v av2[16];
#pragma unroll
    for (int i = 0; i < 16; i++) av2[i] = (float2v){0.f, 0.f};
    float den = 0.f;

    for (int e = beg + slot; e < end; e += 16) {
        int row = ssrc[e];
        const uint4* tp = (const uint4*)(tb + (size_t)row * 512 + li * 32);
        uint4 ta = tp[0], tb4 = tp[1], tc = tp[2], td = tp[3];
        float2v t0 = up2(ta.x),  t1 = up2(ta.y),  t2 = up2(ta.z),  t3 = up2(ta.w);
        float2v t4 = up2(tb4.x), t5 = up2(tb4.y), t6 = up2(tb4.z), t7 = up2(tb4.w);
        float2v t8 = up2(tc.x),  t9 = up2(tc.y),  t10 = up2(tc.z), t11 = up2(tc.w);
        float2v t12 = up2(td.x), t13 = up2(td.y), t14 = up2(td.z), t15 = up2(td.w);
        float2v d2 = q2[0] * t0;
        d2 += q2[1] * t1;   d2 += q2[2] * t2;   d2 += q2[3] * t3;
        d2 += q2[4] * t4;   d2 += q2[5] * t5;   d2 += q2[6] * t6;
        d2 += q2[7] * t7;   d2 += q2[8] * t8;   d2 += q2[9] * t9;
        d2 += q2[10] * t10; d2 += q2[11] * t11; d2 += q2[12] * t12;
        d2 += q2[13] * t13; d2 += q2[14] * t14; d2 += q2[15] * t15;
        float d = d2.x + d2.y;
        d += __shfl_xor(d, 1, 64);
        d += __shfl_xor(d, 2, 64);
        d += __shfl_xor(d, 4, 64);
        d += __shfl_xor(d, 8, 64);
        float w = __expf(d);
        den += w;
        float2v w2 = {w, w};
        av2[0] += w2 * t0;   av2[1] += w2 * t1;   av2[2] += w2 * t2;
        av2[3] += w2 * t3;   av2[4] += w2 * t4;   av2[5] += w2 * t5;
        av2[6] += w2 * t6;   av2[7] += w2 * t7;   av2[8] += w2 * t8;
        av2[9] += w2 * t9;   av2[10] += w2 * t10; av2[11] += w2 * t11;
        av2[12] += w2 * t12; av2[13] += w2 * t13; av2[14] += w2 * t14;
        av2[15] += w2 * t15;
    }
    // cross-group reduce within the wave (groups all converged here)
#pragma unroll
    for (int off = 16; off < 64; off <<= 1) {
        den += __shfl_xor(den, off, 64);
#pragma unroll
        for (int i = 0; i < 16; i++) {
            av2[i].x += __shfl_xor(av2[i].x, off, 64);
            av2[i].y += __shfl_xor(av2[i].y, off, 64);
        }
    }
    if (grp == 0) {
#pragma unroll
        for (int i = 0; i < 16; i++) {
            sacc[wv][2 * i][li]     = av2[i].x;
            sacc[wv][2 * i + 1][li] = av2[i].y;
        }
    }
    if (ln == 0) sden[wv] = den;
    __syncthreads();
    float inv = 1.0f / (sden[0] + sden[1] + sden[2] + sden[3]);
    int c = tid * 2;                       // dims c, c+1 (c even -> e0 <= 30)
    int l0 = c >> 5, e0 = c & 31;
    float o0 = sacc[0][e0][l0] + sacc[1][e0][l0] + sacc[2][e0][l0] + sacc[3][e0][l0];
    float o1 = sacc[0][e0 + 1][l0] + sacc[1][e0 + 1][l0] + sacc[2][e0 + 1][l0] + sacc[3][e0 + 1][l0];
    attn[(size_t)n * 512 + c]     = f2bf(o0 * inv);
    attn[(size_t)n * 512 + c + 1] = f2bf(o1 * inv);
}

// ---------------- expmap0 in place (R2-verified) ------------------------------
__global__ __launch_bounds__(64) void k_expmap(float* h) {
    int row = blockIdx.x, lane = threadIdx.x;
    floatx4* hp = (floatx4*)(h + (size_t)row * DIMK + lane * 8);
    floatx4 h0 = hp[0], h1 = hp[1];
    float ss = 0.f;
#pragma unroll
    for (int i = 0; i < 4; i++) { ss += h0[i] * h0[i]; ss += h1[i] * h1[i]; }
#pragma unroll
    for (int off = 32; off >= 1; off >>= 1) ss += __shfl_xor(ss, off, 64);
    float n  = sqrtf(ss);
    float nc = fmaxf(n, 1e-7f);
    float fac = tanhf(nc) / nc;
#pragma unroll
    for (int i = 0; i < 4; i++) { h0[i] *= fac; h1[i] *= fac; }
    hp[0] = h0; hp[1] = h1;
}

extern "C" void kernel_launch(void* const* d_in, const int* in_sizes, int n_in,
                              void* d_out, int out_size, void* d_ws, size_t ws_size,
                              hipStream_t stream) {
    const float* x  = (const float*)d_in[0];
    const int* src  = (const int*)d_in[1];
    const int* dst  = (const int*)d_in[2];
    const float* Wq = (const float*)d_in[3];
    const float* bq = (const float*)d_in[4];
    const float* Wk = (const float*)d_in[5];
    const float* Wv = (const float*)d_in[7];
    const float* bv = (const float*)d_in[8];
    const float* Wo = (const float*)d_in[9];
    const float* bo = (const float*)d_in[10];
    float* out = (float*)d_out;

    char* ws = (char*)d_ws;
    const size_t RB  = (size_t)NND * DIMK * 2;     // 20.48 MB bf16 [N,512]
    const size_t WB  = (size_t)DIMK * DIMK * 2;    // 512 KB bf16 [512,512]
    unsigned short* t    = (unsigned short*)(ws);
    unsigned short* qh   = (unsigned short*)(ws + RB);      // attn aliases qh
    unsigned short* WqTs = (unsigned short*)(ws + 2 * RB);
    unsigned short* WkT  = (unsigned short*)(ws + 2 * RB + WB);
    unsigned short* WvT  = (unsigned short*)(ws + 2 * RB + 2 * WB);
    unsigned short* WoB  = (unsigned short*)(ws + 2 * RB + 3 * WB);
    unsigned short* Amat = (unsigned short*)(ws + 2 * RB + 4 * WB);
    unsigned short* Wovb = (unsigned short*)(ws + 2 * RB + 5 * WB);
    float* bh            = (float*)(ws + 2 * RB + 6 * WB);
    float* bpr           = (float*)(ws + 2 * RB + 6 * WB + 2048);
    char* p = ws + 2 * RB + 6 * WB + 4096;
    int* ssrc    = (int*)p;
    int* counts  = ssrc + NE;
    int* offsets = counts + NND;
    int* pos     = offsets + NND + 2;
    unsigned short* attn = qh;   // safe alias: block n reads only qh row n first

    hipMemsetAsync(counts, 0, (size_t)NND * 4, stream);

    const float scf = 0.04419417382415922f;        // 1/sqrt(512)
    k_pre<<<6828, 256, 0, stream>>>(x, Wq, Wk, Wv, Wo, bq, bv, bo, dst, counts,
                                    t, WqTs, WkT, WvT, WoB, bh, bpr, scf);

    // block 0: scan; blocks 1-32: Amat = scf*Wq^T Wk, Wovb = Wo Wv (overlapped)
    k_scan33<<<33, 256, 0, stream>>>(counts, offsets, pos,
                                     WkT, WqTs, WoB, WvT, Amat, Wovb);

    // merged: qh = t @ Amat^T + bh (blocks <640) + edge scatter (blocks >=640)
    k_sg<<<640 + 1250, 256, 0, stream>>>(t, Amat, bh, qh, dst, src, pos, ssrc);

    k_fsa<<<NND, 256, 0, stream>>>(offsets, counts, ssrc, qh, t, attn);

    // out = attn @ Wovb^T + bpr (fp32), expmap in place
    k_proj<<<640, 256, 0, stream>>>(attn, Wovb, bpr, out);
    k_expmap<<<NND, 64, 0, stream>>>(out);
}

// Round 8
// 286.349 us; speedup vs baseline: 5.8309x; 1.2080x over previous
//
#include <hip/hip_runtime.h>
#include <math.h>
#include <stdint.h>

#define NND 20000
#define DIMK 512
#define NE  320000

typedef __attribute__((ext_vector_type(8))) short short8;
typedef __attribute__((ext_vector_type(4))) float floatx4;
typedef __attribute__((ext_vector_type(2))) float float2v;

__device__ inline float bf2f(unsigned short h) {
    unsigned int u = ((unsigned int)h) << 16;
    return __uint_as_float(u);
}
__device__ inline unsigned short f2bf(float f) {
    unsigned int u = __float_as_uint(f);
    unsigned int r = (u + 0x7fffu + ((u >> 16) & 1u)) >> 16;
    return (unsigned short)r;
}
// unpack one u32 (2 bf16) -> float2 {elem0, elem1}
__device__ __forceinline__ float2v up2(unsigned int u) {
    float2v r;
    r.x = __uint_as_float(u << 16);
    r.y = __uint_as_float(u & 0xFFFF0000u);
    return r;
}

__device__ __forceinline__ void gld_lds16(const unsigned short* g, unsigned short* l) {
    __builtin_amdgcn_global_load_lds(
        (const __attribute__((address_space(1))) void*)g,
        (__attribute__((address_space(3))) void*)l,
        16, 0, 0);
}

// ---------------- fused pre-pass ----------------------------------------------
// blocks: [0,5000) logmap -> t bf16; [5000,5256) WoB cvt; [5256,5448) transposes
// (WqTs scaled); [5448,5450) bh; [5450,5578) bpr; [5578,6828) dst histogram
// (histogram now ALSO records each edge's rank = atomicAdd return, so the
// later scatter needs no atomics)
__global__ __launch_bounds__(256) void k_pre(const float* __restrict__ x,
                                             const float* __restrict__ Wq,
                                             const float* __restrict__ Wk,
                                             const float* __restrict__ Wv,
                                             const float* __restrict__ Wo,
                                             const float* __restrict__ bq,
                                             const float* __restrict__ bv,
                                             const float* __restrict__ bo,
                                             const int* __restrict__ dst,
                                             int* __restrict__ counts,
                                             int* __restrict__ rank,
                                             unsigned short* __restrict__ t,
                                             unsigned short* __restrict__ WqTs,
                                             unsigned short* __restrict__ WkT,
                                             unsigned short* __restrict__ WvT,
                                             unsigned short* __restrict__ WoB,
                                             float* __restrict__ bh,
                                             float* __restrict__ bpr,
                                             float scf) {
    int blk = blockIdx.x, tid = threadIdx.x;
    if (blk < 5000) {
        int row = blk * 4 + (tid >> 6);
        int lane = tid & 63;
        const floatx4* xp = (const floatx4*)(x + (size_t)row * DIMK + lane * 8);
        floatx4 x0 = xp[0], x1 = xp[1];
        float ss = 0.f;
#pragma unroll
        for (int i = 0; i < 4; i++) { ss += x0[i] * x0[i]; ss += x1[i] * x1[i]; }
#pragma unroll
        for (int off = 32; off >= 1; off >>= 1) ss += __shfl_xor(ss, off, 64);
        float n  = sqrtf(ss);
        float nc = fminf(fmaxf(n, 1e-7f), 1.0f - 1e-6f);
        float fac = atanhf(nc) / nc;
        union { short8 v; unsigned short u[8]; } o;
#pragma unroll
        for (int i = 0; i < 4; i++) { o.u[i] = f2bf(fac * x0[i]); o.u[4 + i] = f2bf(fac * x1[i]); }
        *(short8*)(t + (size_t)row * DIMK + lane * 8) = o.v;
    } else if (blk < 5256) {
        int i = (blk - 5000) * 256 + tid;
        floatx4 f = *(const floatx4*)(Wo + (size_t)i * 4);
        union { unsigned long long d; unsigned short u[4]; } o;
#pragma unroll
        for (int q = 0; q < 4; q++) o.u[q] = f2bf(f[q]);
        *(unsigned long long*)(WoB + (size_t)i * 4) = o.d;
    } else if (blk < 5448) {
        int g = blk - 5256;
        int m = g >> 6, tile = g & 63;
        int tr = tile >> 3, tc = tile & 7;
        const float* srcm = (m == 0) ? Wq : (m == 1) ? Wk : Wv;
        unsigned short* dstp = (m == 0) ? WqTs : (m == 1) ? WkT : WvT;
        float sc = (m == 0) ? scf : 1.0f;
        __shared__ float tl[64][65];
#pragma unroll
        for (int i = 0; i < 16; i++) {
            int idx = i * 256 + tid; int r = idx >> 6, c = idx & 63;
            tl[c][r] = srcm[(size_t)(tr * 64 + r) * 512 + tc * 64 + c];
        }
        __syncthreads();
#pragma unroll
        for (int i = 0; i < 16; i++) {
            int idx = i * 256 + tid; int r = idx >> 6, c = idx & 63;
            dstp[(size_t)(tc * 64 + r) * 512 + tr * 64 + c] = f2bf(tl[r][c] * sc);
        }
    } else if (blk < 5450) {
        int col = (blk - 5448) * 256 + tid;
        float s = 0.f;
#pragma unroll 8
        for (int m = 0; m < 512; m++) s += bq[m] * Wk[(size_t)m * 512 + col];
        bh[col] = s * scf;
    } else if (blk < 5578) {
        int row = (blk - 5450) * 4 + (tid >> 6);
        int lane = tid & 63;
        const floatx4* wp = (const floatx4*)(Wo + (size_t)row * 512 + lane * 8);
        const floatx4* bp = (const floatx4*)(bv + lane * 8);
        floatx4 a0 = wp[0], a1 = wp[1], c0 = bp[0], c1 = bp[1];
        float s = 0.f;
#pragma unroll
        for (int i = 0; i < 4; i++) { s += a0[i] * c0[i]; s += a1[i] * c1[i]; }
#pragma unroll
        for (int off = 32; off >= 1; off >>= 1) s += __shfl_xor(s, off, 64);
        if (lane == 0) bpr[row] = s + bo[row];
    } else {
        int e = (blk - 5578) * 256 + tid;
        if (e < NE) rank[e] = atomicAdd(&counts[dst[e]], 1);
    }
}

// ---------------- 128x128x512 GEMM tile (R2-verified), device function --------
__device__ __forceinline__ void gemm_tile(int vb,
                                          const unsigned short* __restrict__ A,
                                          const unsigned short* __restrict__ B,
                                          const float* __restrict__ biasf,
                                          unsigned short* __restrict__ out_q,
                                          float* __restrict__ out_f,
                                          int M, int MT, int NT, int Ncols,
                                          unsigned short* smem) {
    int xcd = vb & 7, i = vb >> 3;
    int nt = i % NT, mt = (i / NT) * 8 + xcd;
    if (mt >= MT) return;
    int m0 = mt * 128, n0 = nt * 128;
    int tid = threadIdx.x, wv = tid >> 6, ln = tid & 63;
    int lr = ln & 15, qd = ln >> 4;
    int mh = wv >> 1, nh = wv & 1;

    floatx4 acc[4][4] = {};
    int srow = wv * 16 + (ln >> 2);
    int scol = (((ln & 3) ^ (ln >> 4)) & 3) * 8;
    int fsw = (qd ^ (lr >> 2)) & 3;

    {
        unsigned short* Ab = smem;
        unsigned short* Bb = smem + 8192;
#pragma unroll
        for (int p = 0; p < 2; p++) {
            int tr = p * 64 + srow;
            int ar = m0 + tr; if (ar > M - 1) ar = M - 1;
            gld_lds16(A + (size_t)ar * DIMK + scol, Ab + (p * 64 + wv * 16) * 32);
            gld_lds16(B + (size_t)(n0 + tr) * DIMK + scol, Bb + (p * 64 + wv * 16) * 32);
        }
    }

    for (int it = 0; it < 16; it++) {
        int cur = it & 1, nxt = cur ^ 1;
        __syncthreads();
        if (it + 1 < 16) {
            int kb = (it + 1) * 32;
            unsigned short* Ab = smem + nxt * 4096;
            unsigned short* Bb = smem + 8192 + nxt * 4096;
#pragma unroll
            for (int p = 0; p < 2; p++) {
                int tr = p * 64 + srow;
                int ar = m0 + tr; if (ar > M - 1) ar = M - 1;
                gld_lds16(A + (size_t)ar * DIMK + kb + scol, Ab + (p * 64 + wv * 16) * 32);
                gld_lds16(B + (size_t)(n0 + tr) * DIMK + kb + scol, Bb + (p * 64 + wv * 16) * 32);
            }
        }
        const unsigned short* Ac = smem + cur * 4096;
        const unsigned short* Bc = smem + 8192 + cur * 4096;
        short8 af[4], bfr[4];
#pragma unroll
        for (int mi = 0; mi < 4; mi++)
            af[mi] = *(const short8*)(Ac + (mh * 64 + mi * 16 + lr) * 32 + fsw * 8);
#pragma unroll
        for (int ni = 0; ni < 4; ni++)
            bfr[ni] = *(const short8*)(Bc + (nh * 64 + ni * 16 + lr) * 32 + fsw * 8);
#pragma unroll
        for (int mi = 0; mi < 4; mi++)
#pragma unroll
            for (int ni = 0; ni < 4; ni++)
                acc[mi][ni] = __builtin_amdgcn_mfma_f32_16x16x32_bf16(af[mi], bfr[ni], acc[mi][ni], 0, 0, 0);
    }

    float bb[4];
#pragma unroll
    for (int ni = 0; ni < 4; ni++) bb[ni] = biasf[n0 + nh * 64 + ni * 16 + lr];

    if (!out_f) {
        int col0 = nt * 128;
        unsigned short* cs = smem;
#pragma unroll
        for (int g = 0; g < 4; g++) {
            __syncthreads();
            if (mh == (g >> 1)) {
                int miB = (g & 1) * 2;
#pragma unroll
                for (int m2 = 0; m2 < 2; m2++) {
                    int mi = miB + m2;
                    int lrow = mi * 16 + qd * 4 - (g & 1) * 32;
#pragma unroll
                    for (int ni = 0; ni < 4; ni++) {
                        int col = nh * 64 + ni * 16 + lr;
#pragma unroll
                        for (int r = 0; r < 4; r++)
                            cs[(lrow + r) * 128 + col] = f2bf(acc[mi][ni][r] + bb[ni]);
                    }
                }
            }
            __syncthreads();
#pragma unroll
            for (int itr = 0; itr < 2; itr++) {
                int slot = itr * 256 + tid;
                int row = slot >> 4, cg = slot & 15;
                int gm = m0 + g * 32 + row;
                if (gm < M) {
                    short8 vv = *(const short8*)(cs + row * 128 + cg * 8);
                    *(short8*)(out_q + (size_t)gm * 512 + col0 + cg * 8) = vv;
                }
            }
        }
    } else {
#pragma unroll
        for (int ni = 0; ni < 4; ni++) {
            int gn = n0 + nh * 64 + ni * 16 + lr;
#pragma unroll
            for (int mi = 0; mi < 4; mi++) {
                int gm0 = m0 + mh * 64 + mi * 16 + qd * 4;
#pragma unroll
                for (int r = 0; r < 4; r++) {
                    int gm = gm0 + r;
                    if (gm < M) out_f[(size_t)gm * Ncols + gn] = acc[mi][ni][r] + bb[ni];
                }
            }
        }
    }
}

// ---------------- scan (block 0) + the two 512^3 weight products (blocks 1-32)
__global__ __launch_bounds__(256) void k_scan33(const int* __restrict__ counts,
                                                int* __restrict__ offsets,
                                                const unsigned short* __restrict__ WkT,
                                                const unsigned short* __restrict__ WqTs,
                                                const unsigned short* __restrict__ WoB,
                                                const unsigned short* __restrict__ WvT,
                                                unsigned short* __restrict__ Amat,
                                                unsigned short* __restrict__ Wovb) {
    __shared__ unsigned short smem[16384];
    int tid = threadIdx.x;
    if (blockIdx.x == 0) {
        const int CPT = 79;
        int base = tid * CPT;
        int tot = 0;
        for (int i = 0; i < CPT; i++) {
            int idx = base + i;
            tot += (idx < NND) ? counts[idx] : 0;
        }
        int lane = tid & 63, w = tid >> 6;
        int v = tot;
#pragma unroll
        for (int off = 1; off < 64; off <<= 1) {
            int u = __shfl_up(v, off, 64);
            if (lane >= off) v += u;
        }
        int* wsum = (int*)smem;
        if (lane == 63) wsum[w] = v;
        __syncthreads();
        int wbase = 0;
#pragma unroll
        for (int i = 0; i < 4; i++) wbase += (i < w) ? wsum[i] : 0;
        int run = wbase + (v - tot);
        for (int i = 0; i < CPT; i++) {
            int idx = base + i;
            if (idx < NND) {
                offsets[idx] = run;
                run += counts[idx];
            }
        }
        return;
    }
    int g = blockIdx.x - 1;              // 0..31
    int prod = g >> 4;
    int mt = (g >> 2) & 3, nt = g & 3;
    const unsigned short* A = prod ? WoB : WkT;
    const unsigned short* B = prod ? WvT : WqTs;
    unsigned short* outp = prod ? Wovb : Amat;
    int m0 = mt * 128, n0 = nt * 128;
    int wv = tid >> 6, ln = tid & 63;
    int lr = ln & 15, qd = ln >> 4;
    int mh = wv >> 1, nh = wv & 1;
    floatx4 acc[4][4] = {};
    int srow = wv * 16 + (ln >> 2);
    int scol = (((ln & 3) ^ (ln >> 4)) & 3) * 8;
    int fsw = (qd ^ (lr >> 2)) & 3;
    {
        unsigned short* Ab = smem;
        unsigned short* Bb = smem + 8192;
#pragma unroll
        for (int p = 0; p < 2; p++) {
            int tr = p * 64 + srow;
            gld_lds16(A + (size_t)(m0 + tr) * DIMK + scol, Ab + (p * 64 + wv * 16) * 32);
            gld_lds16(B + (size_t)(n0 + tr) * DIMK + scol, Bb + (p * 64 + wv * 16) * 32);
        }
    }
    for (int it = 0; it < 16; it++) {
        int cur = it & 1, nxt = cur ^ 1;
        __syncthreads();
        if (it + 1 < 16) {
            int kb = (it + 1) * 32;
            unsigned short* Ab = smem + nxt * 4096;
            unsigned short* Bb = smem + 8192 + nxt * 4096;
#pragma unroll
            for (int p = 0; p < 2; p++) {
                int tr = p * 64 + srow;
                gld_lds16(A + (size_t)(m0 + tr) * DIMK + kb + scol, Ab + (p * 64 + wv * 16) * 32);
                gld_lds16(B + (size_t)(n0 + tr) * DIMK + kb + scol, Bb + (p * 64 + wv * 16) * 32);
            }
        }
        const unsigned short* Ac = smem + cur * 4096;
        const unsigned short* Bc = smem + 8192 + cur * 4096;
        short8 af[4], bfr[4];
#pragma unroll
        for (int mi = 0; mi < 4; mi++)
            af[mi] = *(const short8*)(Ac + (mh * 64 + mi * 16 + lr) * 32 + fsw * 8);
#pragma unroll
        for (int ni = 0; ni < 4; ni++)
            bfr[ni] = *(const short8*)(Bc + (nh * 64 + ni * 16 + lr) * 32 + fsw * 8);
#pragma unroll
        for (int mi = 0; mi < 4; mi++)
#pragma unroll
            for (int ni = 0; ni < 4; ni++)
                acc[mi][ni] = __builtin_amdgcn_mfma_f32_16x16x32_bf16(af[mi], bfr[ni], acc[mi][ni], 0, 0, 0);
    }
#pragma unroll
    for (int ni = 0; ni < 4; ni++) {
        int gn = n0 + nh * 64 + ni * 16 + lr;
#pragma unroll
        for (int mi = 0; mi < 4; mi++) {
            int gm0 = m0 + mh * 64 + mi * 16 + qd * 4;
#pragma unroll
            for (int r = 0; r < 4; r++)
                outp[(size_t)(gm0 + r) * 512 + gn] = f2bf(acc[mi][ni][r]);
        }
    }
}

// ---------------- merged: qh GEMM (blocks <640) + atomic-free scatter ---------
__global__ __launch_bounds__(256) void k_sg(const unsigned short* __restrict__ t,
                                            const unsigned short* __restrict__ Amat,
                                            const float* __restrict__ bh,
                                            unsigned short* __restrict__ qh,
                                            const int* __restrict__ dst,
                                            const int* __restrict__ src,
                                            const int* __restrict__ offsets,
                                            const int* __restrict__ rank,
                                            int* __restrict__ ssrc) {
    __shared__ unsigned short smem[16384];
    int b = blockIdx.x;
    if (b < 640) {
        gemm_tile(b, t, Amat, bh, qh, nullptr, NND, 157, 4, 512, smem);
    } else {
        int e = (b - 640) * 256 + threadIdx.x;
        if (e < NE) ssrc[offsets[dst[e]] + rank[e]] = src[e];
    }
}

// ---------------- proj GEMM (fp32 out) ----------------------------------------
__global__ __launch_bounds__(256) void k_proj(const unsigned short* __restrict__ A,
                                              const unsigned short* __restrict__ B,
                                              const float* __restrict__ biasf,
                                              float* __restrict__ out_f) {
    __shared__ unsigned short smem[16384];
    gemm_tile(blockIdx.x, A, B, biasf, nullptr, out_f, NND, 157, 4, 512, smem);
}

// ---------------- fused score+softmax+aggregate -------------------------------
// R2-verified 64-lane-per-edge shape (right for avg degree 16: tiny epilogue),
// with packed float2v math (v_pk_fma_f32): dot+accumulate FMA count halved.
__global__ __launch_bounds__(256) void k_fsa(const int* __restrict__ offsets,
                                             const int* __restrict__ counts,
                                             const int* __restrict__ ssrc,
                                             const unsigned short* __restrict__ qb,
                                             const unsigned short* __restrict__ tb,
                                             unsigned short* __restrict__ attn) {
    __shared__ float sacc[4][512];
    __shared__ float sden[4];
    int n = blockIdx.x, tid = threadIdx.x, wv = tid >> 6, ln = tid & 63;
    int beg = offsets[n], end = beg + counts[n];
    uint4 qu = *(const uint4*)(qb + (size_t)n * 512 + ln * 8);
    float2v q0 = up2(qu.x), q1 = up2(qu.y), q2 = up2(qu.z), q3 = up2(qu.w);
    float2v av0 = {0, 0}, av1 = {0, 0}, av2 = {0, 0}, av3 = {0, 0};
    float den = 0.f;
    int i = beg + wv * 2;
    for (; i + 1 < end; i += 8) {
        uint4 ta = *(const uint4*)(tb + (size_t)ssrc[i] * 512 + ln * 8);
        uint4 tc = *(const uint4*)(tb + (size_t)ssrc[i + 1] * 512 + ln * 8);
        float2v t00 = up2(ta.x), t01 = up2(ta.y), t02 = up2(ta.z), t03 = up2(ta.w);
        float2v t10 = up2(tc.x), t11 = up2(tc.y), t12 = up2(tc.z), t13 = up2(tc.w);
        float2v a0 = q0 * t00; a0 += q1 * t01; a0 += q2 * t02; a0 += q3 * t03;
        float2v a1 = q0 * t10; a1 += q1 * t11; a1 += q2 * t12; a1 += q3 * t13;
        float d0 = a0.x + a0.y, d1 = a1.x + a1.y;
#pragma unroll
        for (int off = 32; off >= 1; off >>= 1) {
            d0 += __shfl_xor(d0, off, 64);
            d1 += __shfl_xor(d1, off, 64);
        }
        float w0 = __expf(d0), w1 = __expf(d1);
        den += w0 + w1;
        float2v W0 = {w0, w0}, W1 = {w1, w1};
        av0 += W0 * t00; av0 += W1 * t10;
        av1 += W0 * t01; av1 += W1 * t11;
        av2 += W0 * t02; av2 += W1 * t12;
        av3 += W0 * t03; av3 += W1 * t13;
    }
    if (i < end) {
        uint4 ta = *(const uint4*)(tb + (size_t)ssrc[i] * 512 + ln * 8);
        float2v t00 = up2(ta.x), t01 = up2(ta.y), t02 = up2(ta.z), t03 = up2(ta.w);
        float2v a0 = q0 * t00; a0 += q1 * t01; a0 += q2 * t02; a0 += q3 * t03;
        float d0 = a0.x + a0.y;
#pragma unroll
        for (int off = 32; off >= 1; off >>= 1) d0 += __shfl_xor(d0, off, 64);
        float w0 = __expf(d0);
        den += w0;
        float2v W0 = {w0, w0};
        av0 += W0 * t00; av1 += W0 * t01; av2 += W0 * t02; av3 += W0 * t03;
    }
    floatx4 s0v = {av0.x, av0.y, av1.x, av1.y};
    floatx4 s1v = {av2.x, av2.y, av3.x, av3.y};
    *(floatx4*)&sacc[wv][ln * 8]     = s0v;
    *(floatx4*)&sacc[wv][ln * 8 + 4] = s1v;
    if (ln == 0) sden[wv] = den;
    __syncthreads();
    float inv = 1.0f / (sden[0] + sden[1] + sden[2] + sden[3]);
    int c = tid * 2;
    float o0 = sacc[0][c] + sacc[1][c] + sacc[2][c] + sacc[3][c];
    float o1 = sacc[0][c + 1] + sacc[1][c + 1] + sacc[2][c + 1] + sacc[3][c + 1];
    attn[(size_t)n * 512 + c]     = f2bf(o0 * inv);
    attn[(size_t)n * 512 + c + 1] = f2bf(o1 * inv);
}

// ---------------- expmap0 in place --------------------------------------------
__global__ __launch_bounds__(256) void k_expmap(float* h) {
    int row = blockIdx.x * 4 + (threadIdx.x >> 6);
    int lane = threadIdx.x & 63;
    floatx4* hp = (floatx4*)(h + (size_t)row * DIMK + lane * 8);
    floatx4 h0 = hp[0], h1 = hp[1];
    float ss = 0.f;
#pragma unroll
    for (int i = 0; i < 4; i++) { ss += h0[i] * h0[i]; ss += h1[i] * h1[i]; }
#pragma unroll
    for (int off = 32; off >= 1; off >>= 1) ss += __shfl_xor(ss, off, 64);
    float n  = sqrtf(ss);
    float nc = fmaxf(n, 1e-7f);
    float fac = tanhf(nc) / nc;
#pragma unroll
    for (int i = 0; i < 4; i++) { h0[i] *= fac; h1[i] *= fac; }
    hp[0] = h0; hp[1] = h1;
}

extern "C" void kernel_launch(void* const* d_in, const int* in_sizes, int n_in,
                              void* d_out, int out_size, void* d_ws, size_t ws_size,
                              hipStream_t stream) {
    const float* x  = (const float*)d_in[0];
    const int* src  = (const int*)d_in[1];
    const int* dst  = (const int*)d_in[2];
    const float* Wq = (const float*)d_in[3];
    const float* bq = (const float*)d_in[4];
    const float* Wk = (const float*)d_in[5];
    const float* Wv = (const float*)d_in[7];
    const float* bv = (const float*)d_in[8];
    const float* Wo = (const float*)d_in[9];
    const float* bo = (const float*)d_in[10];
    float* out = (float*)d_out;

    char* ws = (char*)d_ws;
    const size_t RB  = (size_t)NND * DIMK * 2;     // 20.48 MB bf16 [N,512]
    const size_t WB  = (size_t)DIMK * DIMK * 2;    // 512 KB bf16 [512,512]
    unsigned short* t    = (unsigned short*)(ws);
    unsigned short* qh   = (unsigned short*)(ws + RB);      // attn aliases qh
    unsigned short* WqTs = (unsigned short*)(ws + 2 * RB);
    unsigned short* WkT  = (unsigned short*)(ws + 2 * RB + WB);
    unsigned short* WvT  = (unsigned short*)(ws + 2 * RB + 2 * WB);
    unsigned short* WoB  = (unsigned short*)(ws + 2 * RB + 3 * WB);
    unsigned short* Amat = (unsigned short*)(ws + 2 * RB + 4 * WB);
    unsigned short* Wovb = (unsigned short*)(ws + 2 * RB + 5 * WB);
    float* bh            = (float*)(ws + 2 * RB + 6 * WB);
    float* bpr           = (float*)(ws + 2 * RB + 6 * WB + 2048);
    char* p = ws + 2 * RB + 6 * WB + 4096;
    int* ssrc    = (int*)p;
    int* counts  = ssrc + NE;
    int* offsets = counts + NND;
    int* rank    = offsets + NND + 2;
    unsigned short* attn = qh;   // safe alias: block n reads only qh row n first

    hipMemsetAsync(counts, 0, (size_t)NND * 4, stream);

    const float scf = 0.04419417382415922f;        // 1/sqrt(512)
    k_pre<<<6828, 256, 0, stream>>>(x, Wq, Wk, Wv, Wo, bq, bv, bo, dst, counts,
                                    rank, t, WqTs, WkT, WvT, WoB, bh, bpr, scf);

    // block 0: scan; blocks 1-32: Amat = scf*Wq^T Wk, Wovb = Wo Wv (overlapped)
    k_scan33<<<33, 256, 0, stream>>>(counts, offsets,
                                     WkT, WqTs, WoB, WvT, Amat, Wovb);

    // merged: qh = t @ Amat^T + bh (blocks <640) + atomic-free scatter
    k_sg<<<640 + 1250, 256, 0, stream>>>(t, Amat, bh, qh, dst, src,
                                         offsets, rank, ssrc);

    k_fsa<<<NND, 256, 0, stream>>>(offsets, counts, ssrc, qh, t, attn);

    // out = attn @ Wovb^T + bpr (fp32), expmap in place
    k_proj<<<640, 256, 0, stream>>>(attn, Wovb, bpr, out);
    k_expmap<<<5000, 256, 0, stream>>>(out);
}